// Round 1
// baseline (667.203 us; speedup 1.0000x reference)
//
#include <hip/hip_runtime.h>

#define N_NODES 50000
#define N_EDGES 600000
#define D_IN 5
#define D_H 128
#define BN_EPS 1e-5f

// ---------------------------------------------------------------------------
// BN0 statistics: per-feature sum & sumsq over nodes (5 features)
// ---------------------------------------------------------------------------
__global__ __launch_bounds__(256) void k_bn0_stats(const float* __restrict__ h,
                                                   float* __restrict__ stats)
{
    __shared__ float ss[D_IN], sq[D_IN];
    int t = threadIdx.x;
    if (t < D_IN) { ss[t] = 0.f; sq[t] = 0.f; }
    __syncthreads();
    int node = blockIdx.x * blockDim.x + t;
    float v[D_IN];
#pragma unroll
    for (int f = 0; f < D_IN; ++f)
        v[f] = (node < N_NODES) ? h[node * D_IN + f] : 0.f;
    int lane = t & 63;
#pragma unroll
    for (int f = 0; f < D_IN; ++f) {
        float s = v[f], q = v[f] * v[f];
        for (int off = 32; off > 0; off >>= 1) {
            s += __shfl_down(s, off);
            q += __shfl_down(q, off);
        }
        if (lane == 0) { atomicAdd(&ss[f], s); atomicAdd(&sq[f], q); }
    }
    __syncthreads();
    if (t < D_IN) {
        atomicAdd(&stats[t], ss[t]);
        atomicAdd(&stats[D_IN + t], sq[t]);
    }
}

// ---------------------------------------------------------------------------
// Per-edge: accumulate weighted degree (dst) and in-degree count (dst)
// ---------------------------------------------------------------------------
__global__ __launch_bounds__(256) void k_deg_count(const int* __restrict__ dst,
                                                   const float* __restrict__ w,
                                                   float* __restrict__ deg,
                                                   int* __restrict__ cnt)
{
    int e = blockIdx.x * blockDim.x + threadIdx.x;
    if (e < N_EDGES) {
        int d = dst[e];
        atomicAdd(deg + d, w[e]);
        atomicAdd(cnt + d, 1);
    }
}

// ---------------------------------------------------------------------------
// Single-block exclusive scan of counts -> rowptr (in place), copy to cursor,
// and compute dis = rsqrt(deg + 1)   (the +1 is the self-loop weight)
// ---------------------------------------------------------------------------
__global__ __launch_bounds__(1024) void k_scan(int* __restrict__ rowptr,
                                               int* __restrict__ cursor,
                                               const float* __restrict__ deg,
                                               float* __restrict__ dis)
{
    __shared__ int sm[1024];
    const int CH = (N_NODES + 1023) / 1024;  // 49
    int t = threadIdx.x;
    int start = t * CH;
    int end = start + CH;
    if (end > N_NODES) end = N_NODES;
    int s = 0;
    for (int i = start; i < end; ++i) s += rowptr[i];
    sm[t] = s;
    __syncthreads();
    for (int off = 1; off < 1024; off <<= 1) {
        int v = (t >= off) ? sm[t - off] : 0;
        __syncthreads();
        sm[t] += v;
        __syncthreads();
    }
    int run = (t == 0) ? 0 : sm[t - 1];
    for (int i = start; i < end; ++i) {
        int c = rowptr[i];
        rowptr[i] = run;
        cursor[i] = run;
        dis[i] = rsqrtf(deg[i] + 1.0f);
        run += c;
    }
    if (t == 1023) rowptr[N_NODES] = sm[1023];
}

// ---------------------------------------------------------------------------
// Fill CSR: per edge compute norm = dis[src]*w*dis[dst], bucket by dst
// ---------------------------------------------------------------------------
__global__ __launch_bounds__(256) void k_fill(const int* __restrict__ src,
                                              const int* __restrict__ dst,
                                              const float* __restrict__ w,
                                              const float* __restrict__ dis,
                                              int* __restrict__ cursor,
                                              int* __restrict__ csr_src,
                                              float* __restrict__ csr_nrm)
{
    int e = blockIdx.x * blockDim.x + threadIdx.x;
    if (e < N_EDGES) {
        int s = src[e], d = dst[e];
        float nm = dis[s] * w[e] * dis[d];
        int pos = atomicAdd(cursor + d, 1);
        csr_src[pos] = s;
        csr_nrm[pos] = nm;
    }
}

// ---------------------------------------------------------------------------
// Aggregate BN0(h) over the graph at width 5 (fused BN0 apply).
// agg[n] = dis[n]^2 * h0[n] + sum_{e:dst=n} norm_e * h0[src_e]
// ---------------------------------------------------------------------------
__global__ __launch_bounds__(256) void k_agg0(const float* __restrict__ h,
                                              const float* __restrict__ stats,
                                              const float* __restrict__ g0,
                                              const float* __restrict__ be0,
                                              const int* __restrict__ rowptr,
                                              const int* __restrict__ csr_src,
                                              const float* __restrict__ csr_nrm,
                                              const float* __restrict__ dis,
                                              float* __restrict__ agg)
{
    int n = blockIdx.x * blockDim.x + threadIdx.x;
    if (n >= N_NODES) return;
    float sc[D_IN], sh[D_IN];
#pragma unroll
    for (int f = 0; f < D_IN; ++f) {
        float m = stats[f] * (1.0f / N_NODES);
        float var = stats[D_IN + f] * (1.0f / N_NODES) - m * m;
        sc[f] = rsqrtf(var + BN_EPS) * g0[f];
        sh[f] = be0[f] - m * sc[f];
    }
    float dn = dis[n];
    float sl = dn * dn;
    float acc[D_IN];
#pragma unroll
    for (int f = 0; f < D_IN; ++f)
        acc[f] = sl * (h[n * D_IN + f] * sc[f] + sh[f]);
    int e0 = rowptr[n], e1 = rowptr[n + 1];
    for (int e = e0; e < e1; ++e) {
        int s = csr_src[e];
        float nm = csr_nrm[e];
#pragma unroll
        for (int f = 0; f < D_IN; ++f)
            acc[f] += nm * (h[s * D_IN + f] * sc[f] + sh[f]);
    }
#pragma unroll
    for (int f = 0; f < D_IN; ++f)
        agg[n * D_IN + f] = acc[f];
}

// ---------------------------------------------------------------------------
// Layer-1 skinny GEMM: x1 = agg0 @ W1 + b1  (K=5), fused BN1 stats.
// MUST be launched with exactly 512 blocks x 256 threads.
// ---------------------------------------------------------------------------
__global__ __launch_bounds__(256) void k_l1(const float* __restrict__ agg,
                                            const float* __restrict__ W1,
                                            const float* __restrict__ b1,
                                            float* __restrict__ x,
                                            float* __restrict__ stats)
{
    __shared__ float sm_s[256], sm_q[256];
    int t = threadIdx.x;
    int idx0 = blockIdx.x * 256 + t;
    int f = idx0 & (D_H - 1);   // constant per thread: stride is a multiple of 128
    float w[D_IN];
#pragma unroll
    for (int k = 0; k < D_IN; ++k) w[k] = W1[k * D_H + f];
    float b = b1[f];
    float s = 0.f, q = 0.f;
    const int stride = 512 * 256;
    for (int idx = idx0; idx < N_NODES * D_H; idx += stride) {
        int n = idx >> 7;
        const float* a = agg + n * D_IN;
        float v = b;
#pragma unroll
        for (int k = 0; k < D_IN; ++k) v += w[k] * a[k];
        x[idx] = v;
        s += v;
        q += v * v;
    }
    sm_s[t] = s;
    sm_q[t] = q;
    __syncthreads();
    if (t < D_H) {
        atomicAdd(stats + t, sm_s[t] + sm_s[t + D_H]);
        atomicAdd(stats + D_H + t, sm_q[t] + sm_q[t + D_H]);
    }
}

// ---------------------------------------------------------------------------
// BN apply + ReLU (in place), stats = [sum(128), sumsq(128)]
// ---------------------------------------------------------------------------
__global__ __launch_bounds__(256) void k_bn_relu(float* __restrict__ x,
                                                 const float* __restrict__ stats,
                                                 const float* __restrict__ g,
                                                 const float* __restrict__ be)
{
    int i4 = blockIdx.x * blockDim.x + threadIdx.x;
    if (i4 >= N_NODES * D_H / 4) return;
    int f0 = (i4 & 31) * 4;
    float4 s4 = *(const float4*)(stats + f0);
    float4 q4 = *(const float4*)(stats + D_H + f0);
    float4 g4 = *(const float4*)(g + f0);
    float4 b4 = *(const float4*)(be + f0);
    float4 v = *(float4*)(x + (size_t)i4 * 4);
    const float inv = 1.0f / N_NODES;
    float m, var, sc, sh, r;
    m = s4.x * inv; var = q4.x * inv - m * m; sc = rsqrtf(var + BN_EPS) * g4.x; sh = b4.x - m * sc;
    r = v.x * sc + sh; v.x = fmaxf(r, 0.f);
    m = s4.y * inv; var = q4.y * inv - m * m; sc = rsqrtf(var + BN_EPS) * g4.y; sh = b4.y - m * sc;
    r = v.y * sc + sh; v.y = fmaxf(r, 0.f);
    m = s4.z * inv; var = q4.z * inv - m * m; sc = rsqrtf(var + BN_EPS) * g4.z; sh = b4.z - m * sc;
    r = v.z * sc + sh; v.z = fmaxf(r, 0.f);
    m = s4.w * inv; var = q4.w * inv - m * m; sc = rsqrtf(var + BN_EPS) * g4.w; sh = b4.w - m * sc;
    r = v.w * sc + sh; v.w = fmaxf(r, 0.f);
    *(float4*)(x + (size_t)i4 * 4) = v;
}

// ---------------------------------------------------------------------------
// 128-wide graph aggregation via CSR. 2 nodes per 256-thread block.
// ---------------------------------------------------------------------------
__global__ __launch_bounds__(256) void k_agg128(const float* __restrict__ h,
                                                const int* __restrict__ rowptr,
                                                const int* __restrict__ csr_src,
                                                const float* __restrict__ csr_nrm,
                                                const float* __restrict__ dis,
                                                float* __restrict__ out)
{
    int n = blockIdx.x * 2 + (threadIdx.x >> 7);
    int f = threadIdx.x & 127;
    if (n >= N_NODES) return;
    float d = dis[n];
    float acc = d * d * h[(size_t)n * D_H + f];
    int e0 = rowptr[n], e1 = rowptr[n + 1];
    for (int e = e0; e < e1; ++e) {
        int s = csr_src[e];
        float nm = csr_nrm[e];
        acc += nm * h[(size_t)s * D_H + f];
    }
    out[(size_t)n * D_H + f] = acc;
}

// ---------------------------------------------------------------------------
// Tiled fp32 GEMM: C[N,128] = A[N,128] @ B[128,128] + bias, fused BN stats.
// 64-node tile, 256 threads, each thread 8 nodes x 4 features.
// ---------------------------------------------------------------------------
__global__ __launch_bounds__(256) void k_gemm128(const float* __restrict__ A,
                                                 const float* __restrict__ B,
                                                 const float* __restrict__ bias,
                                                 float* __restrict__ C,
                                                 float* __restrict__ stats)
{
    __shared__ float at[64 * D_H];   // 32 KB
    __shared__ float sm_s[D_H], sm_q[D_H];
    int t = threadIdx.x;
    int n0 = blockIdx.x * 64;
#pragma unroll
    for (int i = 0; i < 8; ++i) {
        int e = t * 4 + i * 1024;
        int node = n0 + (e >> 7);
        float4 v = make_float4(0.f, 0.f, 0.f, 0.f);
        if (node < N_NODES) v = *(const float4*)(A + (size_t)n0 * D_H + e);
        *(float4*)(at + e) = v;
    }
    if (t < D_H) { sm_s[t] = 0.f; sm_q[t] = 0.f; }
    __syncthreads();
    int fi = t & 31, ng = t >> 5;
    int f0 = fi * 4;
    float4 acc[8];
#pragma unroll
    for (int j = 0; j < 8; ++j) acc[j] = make_float4(0.f, 0.f, 0.f, 0.f);
    for (int k0 = 0; k0 < D_H; k0 += 4) {
        float4 b0 = *(const float4*)(B + (size_t)(k0 + 0) * D_H + f0);
        float4 b1 = *(const float4*)(B + (size_t)(k0 + 1) * D_H + f0);
        float4 b2 = *(const float4*)(B + (size_t)(k0 + 2) * D_H + f0);
        float4 b3 = *(const float4*)(B + (size_t)(k0 + 3) * D_H + f0);
#pragma unroll
        for (int j = 0; j < 8; ++j) {
            const float* ap = at + (ng + j * 8) * D_H + k0;
            float a0 = ap[0], a1 = ap[1], a2 = ap[2], a3 = ap[3];
            acc[j].x += a0 * b0.x + a1 * b1.x + a2 * b2.x + a3 * b3.x;
            acc[j].y += a0 * b0.y + a1 * b1.y + a2 * b2.y + a3 * b3.y;
            acc[j].z += a0 * b0.z + a1 * b1.z + a2 * b2.z + a3 * b3.z;
            acc[j].w += a0 * b0.w + a1 * b1.w + a2 * b2.w + a3 * b3.w;
        }
    }
    float4 bv = *(const float4*)(bias + f0);
    float4 ls = make_float4(0.f, 0.f, 0.f, 0.f);
    float4 lq = make_float4(0.f, 0.f, 0.f, 0.f);
#pragma unroll
    for (int j = 0; j < 8; ++j) {
        int node = n0 + ng + j * 8;
        if (node < N_NODES) {
            float4 r;
            r.x = acc[j].x + bv.x; r.y = acc[j].y + bv.y;
            r.z = acc[j].z + bv.z; r.w = acc[j].w + bv.w;
            *(float4*)(C + (size_t)node * D_H + f0) = r;
            ls.x += r.x; ls.y += r.y; ls.z += r.z; ls.w += r.w;
            lq.x += r.x * r.x; lq.y += r.y * r.y; lq.z += r.z * r.z; lq.w += r.w * r.w;
        }
    }
    atomicAdd(&sm_s[f0 + 0], ls.x); atomicAdd(&sm_s[f0 + 1], ls.y);
    atomicAdd(&sm_s[f0 + 2], ls.z); atomicAdd(&sm_s[f0 + 3], ls.w);
    atomicAdd(&sm_q[f0 + 0], lq.x); atomicAdd(&sm_q[f0 + 1], lq.y);
    atomicAdd(&sm_q[f0 + 2], lq.z); atomicAdd(&sm_q[f0 + 3], lq.w);
    __syncthreads();
    if (t < D_H) {
        atomicAdd(stats + t, sm_s[t]);
        atomicAdd(stats + D_H + t, sm_q[t]);
    }
}

// ---------------------------------------------------------------------------
// Final dual GEMM: mu = h2@Wmu+bmu -> out[0:N*128), ls = h2@Wls+bls -> rest.
// 32-node tile, 256 threads (features 0..255 across both matrices).
// ---------------------------------------------------------------------------
__global__ __launch_bounds__(256) void k_gemm_out(const float* __restrict__ A,
                                                  const float* __restrict__ Bmu,
                                                  const float* __restrict__ bmu,
                                                  const float* __restrict__ Bls,
                                                  const float* __restrict__ bls,
                                                  float* __restrict__ out)
{
    __shared__ float at[32 * D_H];   // 16 KB
    int t = threadIdx.x;
    int n0 = blockIdx.x * 32;
#pragma unroll
    for (int i = 0; i < 4; ++i) {
        int e = t * 4 + i * 1024;
        int node = n0 + (e >> 7);
        float4 v = make_float4(0.f, 0.f, 0.f, 0.f);
        if (node < N_NODES) v = *(const float4*)(A + (size_t)n0 * D_H + e);
        *(float4*)(at + e) = v;
    }
    __syncthreads();
    int fi = t & 63, ng = t >> 6;
    int f0 = fi * 4;
    const float* B;
    const float* bias;
    float* C;
    int fo;
    if (f0 < D_H) { B = Bmu; bias = bmu; C = out; fo = f0; }
    else { B = Bls; bias = bls; C = out + (size_t)N_NODES * D_H; fo = f0 - D_H; }
    float4 acc[8];
#pragma unroll
    for (int j = 0; j < 8; ++j) acc[j] = make_float4(0.f, 0.f, 0.f, 0.f);
    for (int k0 = 0; k0 < D_H; k0 += 4) {
        float4 b0 = *(const float4*)(B + (size_t)(k0 + 0) * D_H + fo);
        float4 b1 = *(const float4*)(B + (size_t)(k0 + 1) * D_H + fo);
        float4 b2 = *(const float4*)(B + (size_t)(k0 + 2) * D_H + fo);
        float4 b3 = *(const float4*)(B + (size_t)(k0 + 3) * D_H + fo);
#pragma unroll
        for (int j = 0; j < 8; ++j) {
            const float* ap = at + (ng + j * 4) * D_H + k0;
            float a0 = ap[0], a1 = ap[1], a2 = ap[2], a3 = ap[3];
            acc[j].x += a0 * b0.x + a1 * b1.x + a2 * b2.x + a3 * b3.x;
            acc[j].y += a0 * b0.y + a1 * b1.y + a2 * b2.y + a3 * b3.y;
            acc[j].z += a0 * b0.z + a1 * b1.z + a2 * b2.z + a3 * b3.z;
            acc[j].w += a0 * b0.w + a1 * b1.w + a2 * b2.w + a3 * b3.w;
        }
    }
    float4 bv = *(const float4*)(bias + fo);
#pragma unroll
    for (int j = 0; j < 8; ++j) {
        int node = n0 + ng + j * 4;
        if (node < N_NODES) {
            float4 r;
            r.x = acc[j].x + bv.x; r.y = acc[j].y + bv.y;
            r.z = acc[j].z + bv.z; r.w = acc[j].w + bv.w;
            *(float4*)(C + (size_t)node * D_H + fo) = r;
        }
    }
}

// ---------------------------------------------------------------------------
extern "C" void kernel_launch(void* const* d_in, const int* in_sizes, int n_in,
                              void* d_out, int out_size, void* d_ws, size_t ws_size,
                              hipStream_t stream)
{
    const float* h   = (const float*)d_in[0];
    const int*   eidx = (const int*)d_in[1];
    const float* ew  = (const float*)d_in[2];
    const float* g0  = (const float*)d_in[3];
    const float* be0 = (const float*)d_in[4];
    const float* W1  = (const float*)d_in[5];
    const float* b1  = (const float*)d_in[6];
    const float* g1  = (const float*)d_in[7];
    const float* be1 = (const float*)d_in[8];
    const float* W2  = (const float*)d_in[9];
    const float* b2  = (const float*)d_in[10];
    const float* g2  = (const float*)d_in[11];
    const float* be2 = (const float*)d_in[12];
    const float* Wmu = (const float*)d_in[13];
    const float* bmu = (const float*)d_in[14];
    const float* Wls = (const float*)d_in[15];
    const float* bls = (const float*)d_in[16];
    const int* srcv = eidx;
    const int* dstv = eidx + N_EDGES;
    float* out = (float*)d_out;

    char* ws = (char*)d_ws;
    size_t off = 0;
    auto alloc = [&](size_t bytes) -> char* {
        char* p = ws + off;
        off += (bytes + 255) & ~(size_t)255;
        return p;
    };
    float* stats0  = (float*)alloc(16 * 4);
    float* stats1  = (float*)alloc(256 * 4);
    float* stats2  = (float*)alloc(256 * 4);
    float* deg     = (float*)alloc(N_NODES * 4);
    int*   rowptr  = (int*)  alloc((N_NODES + 1) * 4);
    size_t zero_bytes = off;                 // everything above must start at 0
    float* dis     = (float*)alloc(N_NODES * 4);
    int*   cursor  = (int*)  alloc(N_NODES * 4);
    int*   csr_src = (int*)  alloc(N_EDGES * 4);
    float* csr_nrm = (float*)alloc(N_EDGES * 4);
    float* agg0    = (float*)alloc(N_NODES * D_IN * 4);
    float* bufA    = (float*)alloc((size_t)N_NODES * D_H * 4);
    float* bufB    = (float*)alloc((size_t)N_NODES * D_H * 4);
    (void)ws_size; (void)in_sizes; (void)n_in; (void)out_size;

    hipMemsetAsync(d_ws, 0, zero_bytes, stream);

    k_bn0_stats<<<(N_NODES + 255) / 256, 256, 0, stream>>>(h, stats0);
    k_deg_count<<<(N_EDGES + 255) / 256, 256, 0, stream>>>(dstv, ew, deg, rowptr);
    k_scan<<<1, 1024, 0, stream>>>(rowptr, cursor, deg, dis);
    k_fill<<<(N_EDGES + 255) / 256, 256, 0, stream>>>(srcv, dstv, ew, dis, cursor,
                                                      csr_src, csr_nrm);
    k_agg0<<<(N_NODES + 255) / 256, 256, 0, stream>>>(h, stats0, g0, be0, rowptr,
                                                      csr_src, csr_nrm, dis, agg0);
    k_l1<<<512, 256, 0, stream>>>(agg0, W1, b1, bufA, stats1);
    k_bn_relu<<<(N_NODES * D_H / 4 + 255) / 256, 256, 0, stream>>>(bufA, stats1, g1, be1);
    k_agg128<<<(N_NODES + 1) / 2, 256, 0, stream>>>(bufA, rowptr, csr_src, csr_nrm,
                                                    dis, bufB);
    k_gemm128<<<(N_NODES + 63) / 64, 256, 0, stream>>>(bufB, W2, b2, bufA, stats2);
    k_bn_relu<<<(N_NODES * D_H / 4 + 255) / 256, 256, 0, stream>>>(bufA, stats2, g2, be2);
    k_gemm_out<<<(N_NODES + 31) / 32, 256, 0, stream>>>(bufA, Wmu, bmu, Wls, bls, out);
}

// Round 2
// 493.413 us; speedup vs baseline: 1.3522x; 1.3522x over previous
//
#include <hip/hip_runtime.h>

#define N_NODES 50000
#define N_EDGES 600000
#define D_IN 5
#define D_H 128
#define BN_EPS 1e-5f
#define SCAN_BLOCKS ((N_NODES + 255) / 256)   // 196

// ---------------------------------------------------------------------------
// BN0 statistics: per-feature sum & sumsq over nodes (5 features)
// ---------------------------------------------------------------------------
__global__ __launch_bounds__(256) void k_bn0_stats(const float* __restrict__ h,
                                                   float* __restrict__ stats)
{
    __shared__ float ss[D_IN], sq[D_IN];
    int t = threadIdx.x;
    if (t < D_IN) { ss[t] = 0.f; sq[t] = 0.f; }
    __syncthreads();
    int node = blockIdx.x * blockDim.x + t;
    float v[D_IN];
#pragma unroll
    for (int f = 0; f < D_IN; ++f)
        v[f] = (node < N_NODES) ? h[node * D_IN + f] : 0.f;
    int lane = t & 63;
#pragma unroll
    for (int f = 0; f < D_IN; ++f) {
        float s = v[f], q = v[f] * v[f];
        for (int off = 32; off > 0; off >>= 1) {
            s += __shfl_down(s, off);
            q += __shfl_down(q, off);
        }
        if (lane == 0) { atomicAdd(&ss[f], s); atomicAdd(&sq[f], q); }
    }
    __syncthreads();
    if (t < D_IN) {
        atomicAdd(&stats[t], ss[t]);
        atomicAdd(&stats[D_IN + t], sq[t]);
    }
}

// ---------------------------------------------------------------------------
// Per-edge: accumulate weighted degree (dst) and in-degree count (dst)
// counts are accumulated into rowptr[]
// ---------------------------------------------------------------------------
__global__ __launch_bounds__(256) void k_deg_count(const int* __restrict__ dst,
                                                   const float* __restrict__ w,
                                                   float* __restrict__ deg,
                                                   int* __restrict__ cnt)
{
    int e = blockIdx.x * blockDim.x + threadIdx.x;
    if (e < N_EDGES) {
        int d = dst[e];
        atomicAdd(deg + d, w[e]);
        atomicAdd(cnt + d, 1);
    }
}

// ---------------------------------------------------------------------------
// Scan pass 1: per-block sum of counts -> blocksums; also dis = rsqrt(deg+1)
// ---------------------------------------------------------------------------
__global__ __launch_bounds__(256) void k_scan1(const int* __restrict__ cnt,
                                               const float* __restrict__ deg,
                                               float* __restrict__ dis,
                                               int* __restrict__ blocksums)
{
    __shared__ int sm[256];
    int t = threadIdx.x;
    int i = blockIdx.x * 256 + t;
    int c = (i < N_NODES) ? cnt[i] : 0;
    if (i < N_NODES) dis[i] = rsqrtf(deg[i] + 1.0f);
    sm[t] = c;
    __syncthreads();
    for (int off = 128; off > 0; off >>= 1) {
        if (t < off) sm[t] += sm[t + off];
        __syncthreads();
    }
    if (t == 0) blocksums[blockIdx.x] = sm[0];
}

// ---------------------------------------------------------------------------
// Scan pass 2: single block exclusive scan of block sums (196 <= 256)
// also writes rowptr[N_NODES] = total edge count
// ---------------------------------------------------------------------------
__global__ __launch_bounds__(256) void k_scan2(int* __restrict__ blocksums,
                                               int* __restrict__ rowptr)
{
    __shared__ int sm[256];
    int t = threadIdx.x;
    int c = (t < SCAN_BLOCKS) ? blocksums[t] : 0;
    sm[t] = c;
    __syncthreads();
    for (int off = 1; off < 256; off <<= 1) {
        int v = (t >= off) ? sm[t - off] : 0;
        __syncthreads();
        sm[t] += v;
        __syncthreads();
    }
    // exclusive offsets
    if (t < SCAN_BLOCKS) blocksums[t] = sm[t] - c;
    if (t == 255) rowptr[N_NODES] = sm[255];
}

// ---------------------------------------------------------------------------
// Scan pass 3: per-block exclusive scan + block offset -> rowptr & cursor
// (reads counts from rowptr, overwrites rowptr in place)
// ---------------------------------------------------------------------------
__global__ __launch_bounds__(256) void k_scan3(int* __restrict__ rowptr,
                                               int* __restrict__ cursor,
                                               const int* __restrict__ blocksums)
{
    __shared__ int sm[256];
    int t = threadIdx.x;
    int i = blockIdx.x * 256 + t;
    int c = (i < N_NODES) ? rowptr[i] : 0;
    sm[t] = c;
    __syncthreads();
    for (int off = 1; off < 256; off <<= 1) {
        int v = (t >= off) ? sm[t - off] : 0;
        __syncthreads();
        sm[t] += v;
        __syncthreads();
    }
    if (i < N_NODES) {
        int pos = blocksums[blockIdx.x] + sm[t] - c;   // exclusive
        rowptr[i] = pos;
        cursor[i] = pos;
    }
}

// ---------------------------------------------------------------------------
// Fill CSR: per edge compute norm = dis[src]*w*dis[dst], bucket by dst
// ---------------------------------------------------------------------------
__global__ __launch_bounds__(256) void k_fill(const int* __restrict__ src,
                                              const int* __restrict__ dst,
                                              const float* __restrict__ w,
                                              const float* __restrict__ dis,
                                              int* __restrict__ cursor,
                                              int* __restrict__ csr_src,
                                              float* __restrict__ csr_nrm)
{
    int e = blockIdx.x * blockDim.x + threadIdx.x;
    if (e < N_EDGES) {
        int s = src[e], d = dst[e];
        float nm = dis[s] * w[e] * dis[d];
        int pos = atomicAdd(cursor + d, 1);
        csr_src[pos] = s;
        csr_nrm[pos] = nm;
    }
}

// ---------------------------------------------------------------------------
// Aggregate BN0(h) over the graph at width 5 (fused BN0 apply).
// agg[n] = dis[n]^2 * h0[n] + sum_{e:dst=n} norm_e * h0[src_e]
// ---------------------------------------------------------------------------
__global__ __launch_bounds__(256) void k_agg0(const float* __restrict__ h,
                                              const float* __restrict__ stats,
                                              const float* __restrict__ g0,
                                              const float* __restrict__ be0,
                                              const int* __restrict__ rowptr,
                                              const int* __restrict__ csr_src,
                                              const float* __restrict__ csr_nrm,
                                              const float* __restrict__ dis,
                                              float* __restrict__ agg)
{
    int n = blockIdx.x * blockDim.x + threadIdx.x;
    if (n >= N_NODES) return;
    float sc[D_IN], sh[D_IN];
#pragma unroll
    for (int f = 0; f < D_IN; ++f) {
        float m = stats[f] * (1.0f / N_NODES);
        float var = stats[D_IN + f] * (1.0f / N_NODES) - m * m;
        sc[f] = rsqrtf(var + BN_EPS) * g0[f];
        sh[f] = be0[f] - m * sc[f];
    }
    float dn = dis[n];
    float sl = dn * dn;
    float acc[D_IN];
#pragma unroll
    for (int f = 0; f < D_IN; ++f)
        acc[f] = sl * (h[n * D_IN + f] * sc[f] + sh[f]);
    int e0 = rowptr[n], e1 = rowptr[n + 1];
    for (int e = e0; e < e1; ++e) {
        int s = csr_src[e];
        float nm = csr_nrm[e];
#pragma unroll
        for (int f = 0; f < D_IN; ++f)
            acc[f] += nm * (h[s * D_IN + f] * sc[f] + sh[f]);
    }
#pragma unroll
    for (int f = 0; f < D_IN; ++f)
        agg[n * D_IN + f] = acc[f];
}

// ---------------------------------------------------------------------------
// Layer-1 skinny GEMM: x1 = agg0 @ W1 + b1  (K=5), fused BN1 stats.
// MUST be launched with exactly 512 blocks x 256 threads.
// ---------------------------------------------------------------------------
__global__ __launch_bounds__(256) void k_l1(const float* __restrict__ agg,
                                            const float* __restrict__ W1,
                                            const float* __restrict__ b1,
                                            float* __restrict__ x,
                                            float* __restrict__ stats)
{
    __shared__ float sm_s[256], sm_q[256];
    int t = threadIdx.x;
    int idx0 = blockIdx.x * 256 + t;
    int f = idx0 & (D_H - 1);   // constant per thread: stride is a multiple of 128
    float w[D_IN];
#pragma unroll
    for (int k = 0; k < D_IN; ++k) w[k] = W1[k * D_H + f];
    float b = b1[f];
    float s = 0.f, q = 0.f;
    const int stride = 512 * 256;
    for (int idx = idx0; idx < N_NODES * D_H; idx += stride) {
        int n = idx >> 7;
        const float* a = agg + n * D_IN;
        float v = b;
#pragma unroll
        for (int k = 0; k < D_IN; ++k) v += w[k] * a[k];
        x[idx] = v;
        s += v;
        q += v * v;
    }
    sm_s[t] = s;
    sm_q[t] = q;
    __syncthreads();
    if (t < D_H) {
        atomicAdd(stats + t, sm_s[t] + sm_s[t + D_H]);
        atomicAdd(stats + D_H + t, sm_q[t] + sm_q[t + D_H]);
    }
}

// ---------------------------------------------------------------------------
// BN apply + ReLU (in place), stats = [sum(128), sumsq(128)]
// ---------------------------------------------------------------------------
__global__ __launch_bounds__(256) void k_bn_relu(float* __restrict__ x,
                                                 const float* __restrict__ stats,
                                                 const float* __restrict__ g,
                                                 const float* __restrict__ be)
{
    int i4 = blockIdx.x * blockDim.x + threadIdx.x;
    if (i4 >= N_NODES * D_H / 4) return;
    int f0 = (i4 & 31) * 4;
    float4 s4 = *(const float4*)(stats + f0);
    float4 q4 = *(const float4*)(stats + D_H + f0);
    float4 g4 = *(const float4*)(g + f0);
    float4 b4 = *(const float4*)(be + f0);
    float4 v = *(float4*)(x + (size_t)i4 * 4);
    const float inv = 1.0f / N_NODES;
    float m, var, sc, sh, r;
    m = s4.x * inv; var = q4.x * inv - m * m; sc = rsqrtf(var + BN_EPS) * g4.x; sh = b4.x - m * sc;
    r = v.x * sc + sh; v.x = fmaxf(r, 0.f);
    m = s4.y * inv; var = q4.y * inv - m * m; sc = rsqrtf(var + BN_EPS) * g4.y; sh = b4.y - m * sc;
    r = v.y * sc + sh; v.y = fmaxf(r, 0.f);
    m = s4.z * inv; var = q4.z * inv - m * m; sc = rsqrtf(var + BN_EPS) * g4.z; sh = b4.z - m * sc;
    r = v.z * sc + sh; v.z = fmaxf(r, 0.f);
    m = s4.w * inv; var = q4.w * inv - m * m; sc = rsqrtf(var + BN_EPS) * g4.w; sh = b4.w - m * sc;
    r = v.w * sc + sh; v.w = fmaxf(r, 0.f);
    *(float4*)(x + (size_t)i4 * 4) = v;
}

// ---------------------------------------------------------------------------
// 128-wide graph aggregation via CSR. 2 nodes per 256-thread block.
// ---------------------------------------------------------------------------
__global__ __launch_bounds__(256) void k_agg128(const float* __restrict__ h,
                                                const int* __restrict__ rowptr,
                                                const int* __restrict__ csr_src,
                                                const float* __restrict__ csr_nrm,
                                                const float* __restrict__ dis,
                                                float* __restrict__ out)
{
    int n = blockIdx.x * 2 + (threadIdx.x >> 7);
    int f = threadIdx.x & 127;
    if (n >= N_NODES) return;
    float d = dis[n];
    float acc = d * d * h[(size_t)n * D_H + f];
    int e0 = rowptr[n], e1 = rowptr[n + 1];
    for (int e = e0; e < e1; ++e) {
        int s = csr_src[e];
        float nm = csr_nrm[e];
        acc += nm * h[(size_t)s * D_H + f];
    }
    out[(size_t)n * D_H + f] = acc;
}

// ---------------------------------------------------------------------------
// Tiled fp32 GEMM: C[N,128] = A[N,128] @ B[128,128] + bias, fused BN stats.
// 64-node tile, 256 threads, each thread 8 nodes x 4 features.
// ---------------------------------------------------------------------------
__global__ __launch_bounds__(256) void k_gemm128(const float* __restrict__ A,
                                                 const float* __restrict__ B,
                                                 const float* __restrict__ bias,
                                                 float* __restrict__ C,
                                                 float* __restrict__ stats)
{
    __shared__ float at[64 * D_H];   // 32 KB
    __shared__ float sm_s[D_H], sm_q[D_H];
    int t = threadIdx.x;
    int n0 = blockIdx.x * 64;
#pragma unroll
    for (int i = 0; i < 8; ++i) {
        int e = t * 4 + i * 1024;
        int node = n0 + (e >> 7);
        float4 v = make_float4(0.f, 0.f, 0.f, 0.f);
        if (node < N_NODES) v = *(const float4*)(A + (size_t)n0 * D_H + e);
        *(float4*)(at + e) = v;
    }
    if (t < D_H) { sm_s[t] = 0.f; sm_q[t] = 0.f; }
    __syncthreads();
    int fi = t & 31, ng = t >> 5;
    int f0 = fi * 4;
    float4 acc[8];
#pragma unroll
    for (int j = 0; j < 8; ++j) acc[j] = make_float4(0.f, 0.f, 0.f, 0.f);
    for (int k0 = 0; k0 < D_H; k0 += 4) {
        float4 b0 = *(const float4*)(B + (size_t)(k0 + 0) * D_H + f0);
        float4 b1 = *(const float4*)(B + (size_t)(k0 + 1) * D_H + f0);
        float4 b2 = *(const float4*)(B + (size_t)(k0 + 2) * D_H + f0);
        float4 b3 = *(const float4*)(B + (size_t)(k0 + 3) * D_H + f0);
#pragma unroll
        for (int j = 0; j < 8; ++j) {
            const float* ap = at + (ng + j * 8) * D_H + k0;
            float a0 = ap[0], a1 = ap[1], a2 = ap[2], a3 = ap[3];
            acc[j].x += a0 * b0.x + a1 * b1.x + a2 * b2.x + a3 * b3.x;
            acc[j].y += a0 * b0.y + a1 * b1.y + a2 * b2.y + a3 * b3.y;
            acc[j].z += a0 * b0.z + a1 * b1.z + a2 * b2.z + a3 * b3.z;
            acc[j].w += a0 * b0.w + a1 * b1.w + a2 * b2.w + a3 * b3.w;
        }
    }
    float4 bv = *(const float4*)(bias + f0);
    float4 ls = make_float4(0.f, 0.f, 0.f, 0.f);
    float4 lq = make_float4(0.f, 0.f, 0.f, 0.f);
#pragma unroll
    for (int j = 0; j < 8; ++j) {
        int node = n0 + ng + j * 8;
        if (node < N_NODES) {
            float4 r;
            r.x = acc[j].x + bv.x; r.y = acc[j].y + bv.y;
            r.z = acc[j].z + bv.z; r.w = acc[j].w + bv.w;
            *(float4*)(C + (size_t)node * D_H + f0) = r;
            ls.x += r.x; ls.y += r.y; ls.z += r.z; ls.w += r.w;
            lq.x += r.x * r.x; lq.y += r.y * r.y; lq.z += r.z * r.z; lq.w += r.w * r.w;
        }
    }
    atomicAdd(&sm_s[f0 + 0], ls.x); atomicAdd(&sm_s[f0 + 1], ls.y);
    atomicAdd(&sm_s[f0 + 2], ls.z); atomicAdd(&sm_s[f0 + 3], ls.w);
    atomicAdd(&sm_q[f0 + 0], lq.x); atomicAdd(&sm_q[f0 + 1], lq.y);
    atomicAdd(&sm_q[f0 + 2], lq.z); atomicAdd(&sm_q[f0 + 3], lq.w);
    __syncthreads();
    if (t < D_H) {
        atomicAdd(stats + t, sm_s[t]);
        atomicAdd(stats + D_H + t, sm_q[t]);
    }
}

// ---------------------------------------------------------------------------
// Final dual GEMM: mu = h2@Wmu+bmu -> out[0:N*128), ls = h2@Wls+bls -> rest.
// 32-node tile, 256 threads (features 0..255 across both matrices).
// ---------------------------------------------------------------------------
__global__ __launch_bounds__(256) void k_gemm_out(const float* __restrict__ A,
                                                  const float* __restrict__ Bmu,
                                                  const float* __restrict__ bmu,
                                                  const float* __restrict__ Bls,
                                                  const float* __restrict__ bls,
                                                  float* __restrict__ out)
{
    __shared__ float at[32 * D_H];   // 16 KB
    int t = threadIdx.x;
    int n0 = blockIdx.x * 32;
#pragma unroll
    for (int i = 0; i < 4; ++i) {
        int e = t * 4 + i * 1024;
        int node = n0 + (e >> 7);
        float4 v = make_float4(0.f, 0.f, 0.f, 0.f);
        if (node < N_NODES) v = *(const float4*)(A + (size_t)n0 * D_H + e);
        *(float4*)(at + e) = v;
    }
    __syncthreads();
    int fi = t & 63, ng = t >> 6;
    int f0 = fi * 4;
    const float* B;
    const float* bias;
    float* C;
    int fo;
    if (f0 < D_H) { B = Bmu; bias = bmu; C = out; fo = f0; }
    else { B = Bls; bias = bls; C = out + (size_t)N_NODES * D_H; fo = f0 - D_H; }
    float4 acc[8];
#pragma unroll
    for (int j = 0; j < 8; ++j) acc[j] = make_float4(0.f, 0.f, 0.f, 0.f);
    for (int k0 = 0; k0 < D_H; k0 += 4) {
        float4 b0 = *(const float4*)(B + (size_t)(k0 + 0) * D_H + fo);
        float4 b1 = *(const float4*)(B + (size_t)(k0 + 1) * D_H + fo);
        float4 b2 = *(const float4*)(B + (size_t)(k0 + 2) * D_H + fo);
        float4 b3 = *(const float4*)(B + (size_t)(k0 + 3) * D_H + fo);
#pragma unroll
        for (int j = 0; j < 8; ++j) {
            const float* ap = at + (ng + j * 4) * D_H + k0;
            float a0 = ap[0], a1 = ap[1], a2 = ap[2], a3 = ap[3];
            acc[j].x += a0 * b0.x + a1 * b1.x + a2 * b2.x + a3 * b3.x;
            acc[j].y += a0 * b0.y + a1 * b1.y + a2 * b2.y + a3 * b3.y;
            acc[j].z += a0 * b0.z + a1 * b1.z + a2 * b2.z + a3 * b3.z;
            acc[j].w += a0 * b0.w + a1 * b1.w + a2 * b2.w + a3 * b3.w;
        }
    }
    float4 bv = *(const float4*)(bias + fo);
#pragma unroll
    for (int j = 0; j < 8; ++j) {
        int node = n0 + ng + j * 4;
        if (node < N_NODES) {
            float4 r;
            r.x = acc[j].x + bv.x; r.y = acc[j].y + bv.y;
            r.z = acc[j].z + bv.z; r.w = acc[j].w + bv.w;
            *(float4*)(C + (size_t)node * D_H + fo) = r;
        }
    }
}

// ---------------------------------------------------------------------------
extern "C" void kernel_launch(void* const* d_in, const int* in_sizes, int n_in,
                              void* d_out, int out_size, void* d_ws, size_t ws_size,
                              hipStream_t stream)
{
    const float* h   = (const float*)d_in[0];
    const int*   eidx = (const int*)d_in[1];
    const float* ew  = (const float*)d_in[2];
    const float* g0  = (const float*)d_in[3];
    const float* be0 = (const float*)d_in[4];
    const float* W1  = (const float*)d_in[5];
    const float* b1  = (const float*)d_in[6];
    const float* g1  = (const float*)d_in[7];
    const float* be1 = (const float*)d_in[8];
    const float* W2  = (const float*)d_in[9];
    const float* b2  = (const float*)d_in[10];
    const float* g2  = (const float*)d_in[11];
    const float* be2 = (const float*)d_in[12];
    const float* Wmu = (const float*)d_in[13];
    const float* bmu = (const float*)d_in[14];
    const float* Wls = (const float*)d_in[15];
    const float* bls = (const float*)d_in[16];
    const int* srcv = eidx;
    const int* dstv = eidx + N_EDGES;
    float* out = (float*)d_out;

    char* ws = (char*)d_ws;
    size_t off = 0;
    auto alloc = [&](size_t bytes) -> char* {
        char* p = ws + off;
        off += (bytes + 255) & ~(size_t)255;
        return p;
    };
    float* stats0  = (float*)alloc(16 * 4);
    float* stats1  = (float*)alloc(256 * 4);
    float* stats2  = (float*)alloc(256 * 4);
    float* deg     = (float*)alloc(N_NODES * 4);
    int*   rowptr  = (int*)  alloc((N_NODES + 1) * 4);
    size_t zero_bytes = off;                 // everything above must start at 0
    float* dis     = (float*)alloc(N_NODES * 4);
    int*   cursor  = (int*)  alloc(N_NODES * 4);
    int*   blocksums = (int*)alloc(256 * 4);
    int*   csr_src = (int*)  alloc(N_EDGES * 4);
    float* csr_nrm = (float*)alloc(N_EDGES * 4);
    float* agg0    = (float*)alloc(N_NODES * D_IN * 4);
    float* bufA    = (float*)alloc((size_t)N_NODES * D_H * 4);
    float* bufB    = (float*)alloc((size_t)N_NODES * D_H * 4);
    (void)ws_size; (void)in_sizes; (void)n_in; (void)out_size;

    hipMemsetAsync(d_ws, 0, zero_bytes, stream);

    k_bn0_stats<<<(N_NODES + 255) / 256, 256, 0, stream>>>(h, stats0);
    k_deg_count<<<(N_EDGES + 255) / 256, 256, 0, stream>>>(dstv, ew, deg, rowptr);
    k_scan1<<<SCAN_BLOCKS, 256, 0, stream>>>(rowptr, deg, dis, blocksums);
    k_scan2<<<1, 256, 0, stream>>>(blocksums, rowptr);
    k_scan3<<<SCAN_BLOCKS, 256, 0, stream>>>(rowptr, cursor, blocksums);
    k_fill<<<(N_EDGES + 255) / 256, 256, 0, stream>>>(srcv, dstv, ew, dis, cursor,
                                                      csr_src, csr_nrm);
    k_agg0<<<(N_NODES + 255) / 256, 256, 0, stream>>>(h, stats0, g0, be0, rowptr,
                                                      csr_src, csr_nrm, dis, agg0);
    k_l1<<<512, 256, 0, stream>>>(agg0, W1, b1, bufA, stats1);
    k_bn_relu<<<(N_NODES * D_H / 4 + 255) / 256, 256, 0, stream>>>(bufA, stats1, g1, be1);
    k_agg128<<<(N_NODES + 1) / 2, 256, 0, stream>>>(bufA, rowptr, csr_src, csr_nrm,
                                                    dis, bufB);
    k_gemm128<<<(N_NODES + 63) / 64, 256, 0, stream>>>(bufB, W2, b2, bufA, stats2);
    k_bn_relu<<<(N_NODES * D_H / 4 + 255) / 256, 256, 0, stream>>>(bufA, stats2, g2, be2);
    k_gemm_out<<<(N_NODES + 31) / 32, 256, 0, stream>>>(bufA, Wmu, bmu, Wls, bls, out);
}

// Round 3
// 426.850 us; speedup vs baseline: 1.5631x; 1.1559x over previous
//
#include <hip/hip_runtime.h>

#define N_NODES 50000
#define N_EDGES 600000
#define D_IN 5
#define D_H 128
#define BN_EPS 1e-5f
#define SCAN_BLOCKS ((N_NODES + 255) / 256)   // 196

// ---------------------------------------------------------------------------
// BN0 statistics: per-feature sum & sumsq over nodes (5 features)
// ---------------------------------------------------------------------------
__global__ __launch_bounds__(256) void k_bn0_stats(const float* __restrict__ h,
                                                   float* __restrict__ stats)
{
    __shared__ float ss[D_IN], sq[D_IN];
    int t = threadIdx.x;
    if (t < D_IN) { ss[t] = 0.f; sq[t] = 0.f; }
    __syncthreads();
    int node = blockIdx.x * blockDim.x + t;
    float v[D_IN];
#pragma unroll
    for (int f = 0; f < D_IN; ++f)
        v[f] = (node < N_NODES) ? h[node * D_IN + f] : 0.f;
    int lane = t & 63;
#pragma unroll
    for (int f = 0; f < D_IN; ++f) {
        float s = v[f], q = v[f] * v[f];
        for (int off = 32; off > 0; off >>= 1) {
            s += __shfl_down(s, off);
            q += __shfl_down(q, off);
        }
        if (lane == 0) { atomicAdd(&ss[f], s); atomicAdd(&sq[f], q); }
    }
    __syncthreads();
    if (t < D_IN) {
        atomicAdd(&stats[t], ss[t]);
        atomicAdd(&stats[D_IN + t], sq[t]);
    }
}

// ---------------------------------------------------------------------------
// Per-edge: accumulate weighted degree (dst) and in-degree count (dst)
// counts are accumulated into rowptr[]
// ---------------------------------------------------------------------------
__global__ __launch_bounds__(256) void k_deg_count(const int* __restrict__ dst,
                                                   const float* __restrict__ w,
                                                   float* __restrict__ deg,
                                                   int* __restrict__ cnt)
{
    int e = blockIdx.x * blockDim.x + threadIdx.x;
    if (e < N_EDGES) {
        int d = dst[e];
        atomicAdd(deg + d, w[e]);
        atomicAdd(cnt + d, 1);
    }
}

// ---------------------------------------------------------------------------
// Scan pass 1: per-block sum of counts -> blocksums; also dis = rsqrt(deg+1)
// ---------------------------------------------------------------------------
__global__ __launch_bounds__(256) void k_scan1(const int* __restrict__ cnt,
                                               const float* __restrict__ deg,
                                               float* __restrict__ dis,
                                               int* __restrict__ blocksums)
{
    __shared__ int sm[256];
    int t = threadIdx.x;
    int i = blockIdx.x * 256 + t;
    int c = (i < N_NODES) ? cnt[i] : 0;
    if (i < N_NODES) dis[i] = rsqrtf(deg[i] + 1.0f);
    sm[t] = c;
    __syncthreads();
    for (int off = 128; off > 0; off >>= 1) {
        if (t < off) sm[t] += sm[t + off];
        __syncthreads();
    }
    if (t == 0) blocksums[blockIdx.x] = sm[0];
}

// ---------------------------------------------------------------------------
// Scan pass 2: single block exclusive scan of block sums (196 <= 256)
// also writes rowptr[N_NODES] = total edge count
// ---------------------------------------------------------------------------
__global__ __launch_bounds__(256) void k_scan2(int* __restrict__ blocksums,
                                               int* __restrict__ rowptr)
{
    __shared__ int sm[256];
    int t = threadIdx.x;
    int c = (t < SCAN_BLOCKS) ? blocksums[t] : 0;
    sm[t] = c;
    __syncthreads();
    for (int off = 1; off < 256; off <<= 1) {
        int v = (t >= off) ? sm[t - off] : 0;
        __syncthreads();
        sm[t] += v;
        __syncthreads();
    }
    // exclusive offsets
    if (t < SCAN_BLOCKS) blocksums[t] = sm[t] - c;
    if (t == 255) rowptr[N_NODES] = sm[255];
}

// ---------------------------------------------------------------------------
// Scan pass 3: per-block exclusive scan + block offset -> rowptr & cursor
// (reads counts from rowptr, overwrites rowptr in place)
// ---------------------------------------------------------------------------
__global__ __launch_bounds__(256) void k_scan3(int* __restrict__ rowptr,
                                               int* __restrict__ cursor,
                                               const int* __restrict__ blocksums)
{
    __shared__ int sm[256];
    int t = threadIdx.x;
    int i = blockIdx.x * 256 + t;
    int c = (i < N_NODES) ? rowptr[i] : 0;
    sm[t] = c;
    __syncthreads();
    for (int off = 1; off < 256; off <<= 1) {
        int v = (t >= off) ? sm[t - off] : 0;
        __syncthreads();
        sm[t] += v;
        __syncthreads();
    }
    if (i < N_NODES) {
        int pos = blocksums[blockIdx.x] + sm[t] - c;   // exclusive
        rowptr[i] = pos;
        cursor[i] = pos;
    }
}

// ---------------------------------------------------------------------------
// Fill CSR: per edge compute norm = dis[src]*w*dis[dst], bucket by dst
// ---------------------------------------------------------------------------
__global__ __launch_bounds__(256) void k_fill(const int* __restrict__ src,
                                              const int* __restrict__ dst,
                                              const float* __restrict__ w,
                                              const float* __restrict__ dis,
                                              int* __restrict__ cursor,
                                              int* __restrict__ csr_src,
                                              float* __restrict__ csr_nrm)
{
    int e = blockIdx.x * blockDim.x + threadIdx.x;
    if (e < N_EDGES) {
        int s = src[e], d = dst[e];
        float nm = dis[s] * w[e] * dis[d];
        int pos = atomicAdd(cursor + d, 1);
        csr_src[pos] = s;
        csr_nrm[pos] = nm;
    }
}

// ---------------------------------------------------------------------------
// Aggregate BN0(h) over the graph at width 5 (fused BN0 apply).
// agg[n] = dis[n]^2 * h0[n] + sum_{e:dst=n} norm_e * h0[src_e]
// ---------------------------------------------------------------------------
__global__ __launch_bounds__(256) void k_agg0(const float* __restrict__ h,
                                              const float* __restrict__ stats,
                                              const float* __restrict__ g0,
                                              const float* __restrict__ be0,
                                              const int* __restrict__ rowptr,
                                              const int* __restrict__ csr_src,
                                              const float* __restrict__ csr_nrm,
                                              const float* __restrict__ dis,
                                              float* __restrict__ agg)
{
    int n = blockIdx.x * blockDim.x + threadIdx.x;
    if (n >= N_NODES) return;
    float sc[D_IN], sh[D_IN];
#pragma unroll
    for (int f = 0; f < D_IN; ++f) {
        float m = stats[f] * (1.0f / N_NODES);
        float var = stats[D_IN + f] * (1.0f / N_NODES) - m * m;
        sc[f] = rsqrtf(var + BN_EPS) * g0[f];
        sh[f] = be0[f] - m * sc[f];
    }
    float dn = dis[n];
    float sl = dn * dn;
    float acc[D_IN];
#pragma unroll
    for (int f = 0; f < D_IN; ++f)
        acc[f] = sl * (h[n * D_IN + f] * sc[f] + sh[f]);
    int e0 = rowptr[n], e1 = rowptr[n + 1];
    for (int e = e0; e < e1; ++e) {
        int s = csr_src[e];
        float nm = csr_nrm[e];
#pragma unroll
        for (int f = 0; f < D_IN; ++f)
            acc[f] += nm * (h[s * D_IN + f] * sc[f] + sh[f]);
    }
#pragma unroll
    for (int f = 0; f < D_IN; ++f)
        agg[n * D_IN + f] = acc[f];
}

// ---------------------------------------------------------------------------
// Layer-1 skinny GEMM: x1 = agg0 @ W1 + b1  (K=5), fused BN1 stats.
// MUST be launched with exactly 512 blocks x 256 threads.
// ---------------------------------------------------------------------------
__global__ __launch_bounds__(256) void k_l1(const float* __restrict__ agg,
                                            const float* __restrict__ W1,
                                            const float* __restrict__ b1,
                                            float* __restrict__ x,
                                            float* __restrict__ stats)
{
    __shared__ float sm_s[256], sm_q[256];
    int t = threadIdx.x;
    int idx0 = blockIdx.x * 256 + t;
    int f = idx0 & (D_H - 1);   // constant per thread: stride is a multiple of 128
    float w[D_IN];
#pragma unroll
    for (int k = 0; k < D_IN; ++k) w[k] = W1[k * D_H + f];
    float b = b1[f];
    float s = 0.f, q = 0.f;
    const int stride = 512 * 256;
    for (int idx = idx0; idx < N_NODES * D_H; idx += stride) {
        int n = idx >> 7;
        const float* a = agg + n * D_IN;
        float v = b;
#pragma unroll
        for (int k = 0; k < D_IN; ++k) v += w[k] * a[k];
        x[idx] = v;
        s += v;
        q += v * v;
    }
    sm_s[t] = s;
    sm_q[t] = q;
    __syncthreads();
    if (t < D_H) {
        atomicAdd(stats + t, sm_s[t] + sm_s[t + D_H]);
        atomicAdd(stats + D_H + t, sm_q[t] + sm_q[t + D_H]);
    }
}

// ---------------------------------------------------------------------------
// BN apply + ReLU (in place), stats = [sum(128), sumsq(128)]
// ---------------------------------------------------------------------------
__global__ __launch_bounds__(256) void k_bn_relu(float* __restrict__ x,
                                                 const float* __restrict__ stats,
                                                 const float* __restrict__ g,
                                                 const float* __restrict__ be)
{
    int i4 = blockIdx.x * blockDim.x + threadIdx.x;
    if (i4 >= N_NODES * D_H / 4) return;
    int f0 = (i4 & 31) * 4;
    float4 s4 = *(const float4*)(stats + f0);
    float4 q4 = *(const float4*)(stats + D_H + f0);
    float4 g4 = *(const float4*)(g + f0);
    float4 b4 = *(const float4*)(be + f0);
    float4 v = *(float4*)(x + (size_t)i4 * 4);
    const float inv = 1.0f / N_NODES;
    float m, var, sc, sh, r;
    m = s4.x * inv; var = q4.x * inv - m * m; sc = rsqrtf(var + BN_EPS) * g4.x; sh = b4.x - m * sc;
    r = v.x * sc + sh; v.x = fmaxf(r, 0.f);
    m = s4.y * inv; var = q4.y * inv - m * m; sc = rsqrtf(var + BN_EPS) * g4.y; sh = b4.y - m * sc;
    r = v.y * sc + sh; v.y = fmaxf(r, 0.f);
    m = s4.z * inv; var = q4.z * inv - m * m; sc = rsqrtf(var + BN_EPS) * g4.z; sh = b4.z - m * sc;
    r = v.z * sc + sh; v.z = fmaxf(r, 0.f);
    m = s4.w * inv; var = q4.w * inv - m * m; sc = rsqrtf(var + BN_EPS) * g4.w; sh = b4.w - m * sc;
    r = v.w * sc + sh; v.w = fmaxf(r, 0.f);
    *(float4*)(x + (size_t)i4 * 4) = v;
}

// ---------------------------------------------------------------------------
// 128-wide graph aggregation via CSR. float4/thread, 8 nodes per 256-block,
// edge loop unrolled 4x with prefetched idx/weight for gather MLP.
// ---------------------------------------------------------------------------
__global__ __launch_bounds__(256) void k_agg128(const float* __restrict__ h,
                                                const int* __restrict__ rowptr,
                                                const int* __restrict__ csr_src,
                                                const float* __restrict__ csr_nrm,
                                                const float* __restrict__ dis,
                                                float* __restrict__ out)
{
    int t = threadIdx.x;
    int n = blockIdx.x * 8 + (t >> 5);
    int f0 = (t & 31) * 4;
    if (n >= N_NODES) return;
    float d = dis[n];
    float sl = d * d;
    float4 hv = *(const float4*)(h + (size_t)n * D_H + f0);
    float4 acc;
    acc.x = sl * hv.x; acc.y = sl * hv.y; acc.z = sl * hv.z; acc.w = sl * hv.w;
    int e = rowptr[n], e1 = rowptr[n + 1];
    for (; e + 4 <= e1; e += 4) {
        int s0 = csr_src[e + 0], s1 = csr_src[e + 1];
        int s2 = csr_src[e + 2], s3 = csr_src[e + 3];
        float w0 = csr_nrm[e + 0], w1 = csr_nrm[e + 1];
        float w2 = csr_nrm[e + 2], w3 = csr_nrm[e + 3];
        float4 v0 = *(const float4*)(h + (size_t)s0 * D_H + f0);
        float4 v1 = *(const float4*)(h + (size_t)s1 * D_H + f0);
        float4 v2 = *(const float4*)(h + (size_t)s2 * D_H + f0);
        float4 v3 = *(const float4*)(h + (size_t)s3 * D_H + f0);
        acc.x += w0 * v0.x + w1 * v1.x + w2 * v2.x + w3 * v3.x;
        acc.y += w0 * v0.y + w1 * v1.y + w2 * v2.y + w3 * v3.y;
        acc.z += w0 * v0.z + w1 * v1.z + w2 * v2.z + w3 * v3.z;
        acc.w += w0 * v0.w + w1 * v1.w + w2 * v2.w + w3 * v3.w;
    }
    for (; e < e1; ++e) {
        int s = csr_src[e];
        float nm = csr_nrm[e];
        float4 v = *(const float4*)(h + (size_t)s * D_H + f0);
        acc.x += nm * v.x; acc.y += nm * v.y;
        acc.z += nm * v.z; acc.w += nm * v.w;
    }
    *(float4*)(out + (size_t)n * D_H + f0) = acc;
}

// ---------------------------------------------------------------------------
// Tiled fp32 GEMM: C[N,128] = A[N,128] @ B[128,128] + bias, fused BN stats.
// 64-node tile, 256 threads, each thread 8 nodes x 4 features.
// ---------------------------------------------------------------------------
__global__ __launch_bounds__(256) void k_gemm128(const float* __restrict__ A,
                                                 const float* __restrict__ B,
                                                 const float* __restrict__ bias,
                                                 float* __restrict__ C,
                                                 float* __restrict__ stats)
{
    __shared__ float at[64 * D_H];   // 32 KB
    __shared__ float sm_s[D_H], sm_q[D_H];
    int t = threadIdx.x;
    int n0 = blockIdx.x * 64;
#pragma unroll
    for (int i = 0; i < 8; ++i) {
        int e = t * 4 + i * 1024;
        int node = n0 + (e >> 7);
        float4 v = make_float4(0.f, 0.f, 0.f, 0.f);
        if (node < N_NODES) v = *(const float4*)(A + (size_t)n0 * D_H + e);
        *(float4*)(at + e) = v;
    }
    if (t < D_H) { sm_s[t] = 0.f; sm_q[t] = 0.f; }
    __syncthreads();
    int fi = t & 31, ng = t >> 5;
    int f0 = fi * 4;
    float4 acc[8];
#pragma unroll
    for (int j = 0; j < 8; ++j) acc[j] = make_float4(0.f, 0.f, 0.f, 0.f);
    for (int k0 = 0; k0 < D_H; k0 += 4) {
        float4 b0 = *(const float4*)(B + (size_t)(k0 + 0) * D_H + f0);
        float4 b1 = *(const float4*)(B + (size_t)(k0 + 1) * D_H + f0);
        float4 b2 = *(const float4*)(B + (size_t)(k0 + 2) * D_H + f0);
        float4 b3 = *(const float4*)(B + (size_t)(k0 + 3) * D_H + f0);
#pragma unroll
        for (int j = 0; j < 8; ++j) {
            const float* ap = at + (ng + j * 8) * D_H + k0;
            float a0 = ap[0], a1 = ap[1], a2 = ap[2], a3 = ap[3];
            acc[j].x += a0 * b0.x + a1 * b1.x + a2 * b2.x + a3 * b3.x;
            acc[j].y += a0 * b0.y + a1 * b1.y + a2 * b2.y + a3 * b3.y;
            acc[j].z += a0 * b0.z + a1 * b1.z + a2 * b2.z + a3 * b3.z;
            acc[j].w += a0 * b0.w + a1 * b1.w + a2 * b2.w + a3 * b3.w;
        }
    }
    float4 bv = *(const float4*)(bias + f0);
    float4 ls = make_float4(0.f, 0.f, 0.f, 0.f);
    float4 lq = make_float4(0.f, 0.f, 0.f, 0.f);
#pragma unroll
    for (int j = 0; j < 8; ++j) {
        int node = n0 + ng + j * 8;
        if (node < N_NODES) {
            float4 r;
            r.x = acc[j].x + bv.x; r.y = acc[j].y + bv.y;
            r.z = acc[j].z + bv.z; r.w = acc[j].w + bv.w;
            *(float4*)(C + (size_t)node * D_H + f0) = r;
            ls.x += r.x; ls.y += r.y; ls.z += r.z; ls.w += r.w;
            lq.x += r.x * r.x; lq.y += r.y * r.y; lq.z += r.z * r.z; lq.w += r.w * r.w;
        }
    }
    atomicAdd(&sm_s[f0 + 0], ls.x); atomicAdd(&sm_s[f0 + 1], ls.y);
    atomicAdd(&sm_s[f0 + 2], ls.z); atomicAdd(&sm_s[f0 + 3], ls.w);
    atomicAdd(&sm_q[f0 + 0], lq.x); atomicAdd(&sm_q[f0 + 1], lq.y);
    atomicAdd(&sm_q[f0 + 2], lq.z); atomicAdd(&sm_q[f0 + 3], lq.w);
    __syncthreads();
    if (t < D_H) {
        atomicAdd(stats + t, sm_s[t]);
        atomicAdd(stats + D_H + t, sm_q[t]);
    }
}

// ---------------------------------------------------------------------------
// Final dual GEMM: mu = h2@Wmu+bmu -> out[0:N*128), ls = h2@Wls+bls -> rest.
// 32-node tile, 256 threads (features 0..255 across both matrices).
// ---------------------------------------------------------------------------
__global__ __launch_bounds__(256) void k_gemm_out(const float* __restrict__ A,
                                                  const float* __restrict__ Bmu,
                                                  const float* __restrict__ bmu,
                                                  const float* __restrict__ Bls,
                                                  const float* __restrict__ bls,
                                                  float* __restrict__ out)
{
    __shared__ float at[32 * D_H];   // 16 KB
    int t = threadIdx.x;
    int n0 = blockIdx.x * 32;
#pragma unroll
    for (int i = 0; i < 4; ++i) {
        int e = t * 4 + i * 1024;
        int node = n0 + (e >> 7);
        float4 v = make_float4(0.f, 0.f, 0.f, 0.f);
        if (node < N_NODES) v = *(const float4*)(A + (size_t)n0 * D_H + e);
        *(float4*)(at + e) = v;
    }
    __syncthreads();
    int fi = t & 63, ng = t >> 6;
    int f0 = fi * 4;
    const float* B;
    const float* bias;
    float* C;
    int fo;
    if (f0 < D_H) { B = Bmu; bias = bmu; C = out; fo = f0; }
    else { B = Bls; bias = bls; C = out + (size_t)N_NODES * D_H; fo = f0 - D_H; }
    float4 acc[8];
#pragma unroll
    for (int j = 0; j < 8; ++j) acc[j] = make_float4(0.f, 0.f, 0.f, 0.f);
    for (int k0 = 0; k0 < D_H; k0 += 4) {
        float4 b0 = *(const float4*)(B + (size_t)(k0 + 0) * D_H + fo);
        float4 b1 = *(const float4*)(B + (size_t)(k0 + 1) * D_H + fo);
        float4 b2 = *(const float4*)(B + (size_t)(k0 + 2) * D_H + fo);
        float4 b3 = *(const float4*)(B + (size_t)(k0 + 3) * D_H + fo);
#pragma unroll
        for (int j = 0; j < 8; ++j) {
            const float* ap = at + (ng + j * 4) * D_H + k0;
            float a0 = ap[0], a1 = ap[1], a2 = ap[2], a3 = ap[3];
            acc[j].x += a0 * b0.x + a1 * b1.x + a2 * b2.x + a3 * b3.x;
            acc[j].y += a0 * b0.y + a1 * b1.y + a2 * b2.y + a3 * b3.y;
            acc[j].z += a0 * b0.z + a1 * b1.z + a2 * b2.z + a3 * b3.z;
            acc[j].w += a0 * b0.w + a1 * b1.w + a2 * b2.w + a3 * b3.w;
        }
    }
    float4 bv = *(const float4*)(bias + fo);
#pragma unroll
    for (int j = 0; j < 8; ++j) {
        int node = n0 + ng + j * 4;
        if (node < N_NODES) {
            float4 r;
            r.x = acc[j].x + bv.x; r.y = acc[j].y + bv.y;
            r.z = acc[j].z + bv.z; r.w = acc[j].w + bv.w;
            *(float4*)(C + (size_t)node * D_H + fo) = r;
        }
    }
}

// ---------------------------------------------------------------------------
extern "C" void kernel_launch(void* const* d_in, const int* in_sizes, int n_in,
                              void* d_out, int out_size, void* d_ws, size_t ws_size,
                              hipStream_t stream)
{
    const float* h   = (const float*)d_in[0];
    const int*   eidx = (const int*)d_in[1];
    const float* ew  = (const float*)d_in[2];
    const float* g0  = (const float*)d_in[3];
    const float* be0 = (const float*)d_in[4];
    const float* W1  = (const float*)d_in[5];
    const float* b1  = (const float*)d_in[6];
    const float* g1  = (const float*)d_in[7];
    const float* be1 = (const float*)d_in[8];
    const float* W2  = (const float*)d_in[9];
    const float* b2  = (const float*)d_in[10];
    const float* g2  = (const float*)d_in[11];
    const float* be2 = (const float*)d_in[12];
    const float* Wmu = (const float*)d_in[13];
    const float* bmu = (const float*)d_in[14];
    const float* Wls = (const float*)d_in[15];
    const float* bls = (const float*)d_in[16];
    const int* srcv = eidx;
    const int* dstv = eidx + N_EDGES;
    float* out = (float*)d_out;

    char* ws = (char*)d_ws;
    size_t off = 0;
    auto alloc = [&](size_t bytes) -> char* {
        char* p = ws + off;
        off += (bytes + 255) & ~(size_t)255;
        return p;
    };
    float* stats0  = (float*)alloc(16 * 4);
    float* stats1  = (float*)alloc(256 * 4);
    float* stats2  = (float*)alloc(256 * 4);
    float* deg     = (float*)alloc(N_NODES * 4);
    int*   rowptr  = (int*)  alloc((N_NODES + 1) * 4);
    size_t zero_bytes = off;                 // everything above must start at 0
    float* dis     = (float*)alloc(N_NODES * 4);
    int*   cursor  = (int*)  alloc(N_NODES * 4);
    int*   blocksums = (int*)alloc(256 * 4);
    int*   csr_src = (int*)  alloc(N_EDGES * 4);
    float* csr_nrm = (float*)alloc(N_EDGES * 4);
    float* agg0    = (float*)alloc(N_NODES * D_IN * 4);
    float* bufA    = (float*)alloc((size_t)N_NODES * D_H * 4);
    float* bufB    = (float*)alloc((size_t)N_NODES * D_H * 4);
    (void)ws_size; (void)in_sizes; (void)n_in; (void)out_size;

    hipMemsetAsync(d_ws, 0, zero_bytes, stream);

    k_bn0_stats<<<(N_NODES + 255) / 256, 256, 0, stream>>>(h, stats0);
    k_deg_count<<<(N_EDGES + 255) / 256, 256, 0, stream>>>(dstv, ew, deg, rowptr);
    k_scan1<<<SCAN_BLOCKS, 256, 0, stream>>>(rowptr, deg, dis, blocksums);
    k_scan2<<<1, 256, 0, stream>>>(blocksums, rowptr);
    k_scan3<<<SCAN_BLOCKS, 256, 0, stream>>>(rowptr, cursor, blocksums);
    k_fill<<<(N_EDGES + 255) / 256, 256, 0, stream>>>(srcv, dstv, ew, dis, cursor,
                                                      csr_src, csr_nrm);
    k_agg0<<<(N_NODES + 255) / 256, 256, 0, stream>>>(h, stats0, g0, be0, rowptr,
                                                      csr_src, csr_nrm, dis, agg0);
    k_l1<<<512, 256, 0, stream>>>(agg0, W1, b1, bufA, stats1);
    k_bn_relu<<<(N_NODES * D_H / 4 + 255) / 256, 256, 0, stream>>>(bufA, stats1, g1, be1);
    k_agg128<<<(N_NODES + 7) / 8, 256, 0, stream>>>(bufA, rowptr, csr_src, csr_nrm,
                                                    dis, bufB);
    k_gemm128<<<(N_NODES + 63) / 64, 256, 0, stream>>>(bufB, W2, b2, bufA, stats2);
    k_bn_relu<<<(N_NODES * D_H / 4 + 255) / 256, 256, 0, stream>>>(bufA, stats2, g2, be2);
    k_gemm_out<<<(N_NODES + 31) / 32, 256, 0, stream>>>(bufA, Wmu, bmu, Wls, bls, out);
}

// Round 4
// 386.931 us; speedup vs baseline: 1.7243x; 1.1032x over previous
//
#include <hip/hip_runtime.h>

#define N_NODES 50000
#define N_EDGES 600000
#define D_IN 5
#define D_H 128
#define BN_EPS 1e-5f
#define SCAN_BLOCKS ((N_NODES + 255) / 256)   // 196

typedef __bf16 bf16x8 __attribute__((ext_vector_type(8)));
typedef float  f32x4  __attribute__((ext_vector_type(4)));

__device__ inline unsigned short f2bfb(float f) {          // fp32 -> bf16 bits, RNE
    unsigned u = __builtin_bit_cast(unsigned, f);
    unsigned r = u + 0x7fffu + ((u >> 16) & 1u);
    return (unsigned short)(r >> 16);
}
__device__ inline float bflo(unsigned u) { return __builtin_bit_cast(float, u << 16); }
__device__ inline float bfhi(unsigned u) { return __builtin_bit_cast(float, u & 0xffff0000u); }

// ---------------------------------------------------------------------------
// Weight prep: W[k][n] fp32 -> Wt[n][k] bf16, for W2 / Wmu / Wls
// grid = 192 blocks x 256 thr; 64 blocks per matrix
// ---------------------------------------------------------------------------
__global__ __launch_bounds__(256) void k_wprep(const float* __restrict__ W2,
                                               const float* __restrict__ Wmu,
                                               const float* __restrict__ Wls,
                                               unsigned short* __restrict__ T2,
                                               unsigned short* __restrict__ Tmu,
                                               unsigned short* __restrict__ Tls)
{
    int mat = blockIdx.x >> 6;
    int idx = (blockIdx.x & 63) * 256 + threadIdx.x;   // < 16384
    const float* W = (mat == 0) ? W2 : (mat == 1) ? Wmu : Wls;
    unsigned short* T = (mat == 0) ? T2 : (mat == 1) ? Tmu : Tls;
    int k = idx >> 7, n = idx & 127;
    T[n * D_H + k] = f2bfb(W[idx]);
}

// ---------------------------------------------------------------------------
// BN0 statistics: per-feature sum & sumsq over nodes (5 features)
// ---------------------------------------------------------------------------
__global__ __launch_bounds__(256) void k_bn0_stats(const float* __restrict__ h,
                                                   float* __restrict__ stats)
{
    __shared__ float ss[D_IN], sq[D_IN];
    int t = threadIdx.x;
    if (t < D_IN) { ss[t] = 0.f; sq[t] = 0.f; }
    __syncthreads();
    int node = blockIdx.x * blockDim.x + t;
    float v[D_IN];
#pragma unroll
    for (int f = 0; f < D_IN; ++f)
        v[f] = (node < N_NODES) ? h[node * D_IN + f] : 0.f;
    int lane = t & 63;
#pragma unroll
    for (int f = 0; f < D_IN; ++f) {
        float s = v[f], q = v[f] * v[f];
        for (int off = 32; off > 0; off >>= 1) {
            s += __shfl_down(s, off);
            q += __shfl_down(q, off);
        }
        if (lane == 0) { atomicAdd(&ss[f], s); atomicAdd(&sq[f], q); }
    }
    __syncthreads();
    if (t < D_IN) {
        atomicAdd(&stats[t], ss[t]);
        atomicAdd(&stats[D_IN + t], sq[t]);
    }
}

// ---------------------------------------------------------------------------
__global__ __launch_bounds__(256) void k_deg_count(const int* __restrict__ dst,
                                                   const float* __restrict__ w,
                                                   float* __restrict__ deg,
                                                   int* __restrict__ cnt)
{
    int e = blockIdx.x * blockDim.x + threadIdx.x;
    if (e < N_EDGES) {
        int d = dst[e];
        atomicAdd(deg + d, w[e]);
        atomicAdd(cnt + d, 1);
    }
}

// ---------------------------------------------------------------------------
__global__ __launch_bounds__(256) void k_scan1(const int* __restrict__ cnt,
                                               const float* __restrict__ deg,
                                               float* __restrict__ dis,
                                               int* __restrict__ blocksums)
{
    __shared__ int sm[256];
    int t = threadIdx.x;
    int i = blockIdx.x * 256 + t;
    int c = (i < N_NODES) ? cnt[i] : 0;
    if (i < N_NODES) dis[i] = rsqrtf(deg[i] + 1.0f);
    sm[t] = c;
    __syncthreads();
    for (int off = 128; off > 0; off >>= 1) {
        if (t < off) sm[t] += sm[t + off];
        __syncthreads();
    }
    if (t == 0) blocksums[blockIdx.x] = sm[0];
}

__global__ __launch_bounds__(256) void k_scan2(int* __restrict__ blocksums,
                                               int* __restrict__ rowptr)
{
    __shared__ int sm[256];
    int t = threadIdx.x;
    int c = (t < SCAN_BLOCKS) ? blocksums[t] : 0;
    sm[t] = c;
    __syncthreads();
    for (int off = 1; off < 256; off <<= 1) {
        int v = (t >= off) ? sm[t - off] : 0;
        __syncthreads();
        sm[t] += v;
        __syncthreads();
    }
    if (t < SCAN_BLOCKS) blocksums[t] = sm[t] - c;
    if (t == 255) rowptr[N_NODES] = sm[255];
}

__global__ __launch_bounds__(256) void k_scan3(int* __restrict__ rowptr,
                                               int* __restrict__ cursor,
                                               const int* __restrict__ blocksums)
{
    __shared__ int sm[256];
    int t = threadIdx.x;
    int i = blockIdx.x * 256 + t;
    int c = (i < N_NODES) ? rowptr[i] : 0;
    sm[t] = c;
    __syncthreads();
    for (int off = 1; off < 256; off <<= 1) {
        int v = (t >= off) ? sm[t - off] : 0;
        __syncthreads();
        sm[t] += v;
        __syncthreads();
    }
    if (i < N_NODES) {
        int pos = blocksums[blockIdx.x] + sm[t] - c;
        rowptr[i] = pos;
        cursor[i] = pos;
    }
}

// ---------------------------------------------------------------------------
__global__ __launch_bounds__(256) void k_fill(const int* __restrict__ src,
                                              const int* __restrict__ dst,
                                              const float* __restrict__ w,
                                              const float* __restrict__ dis,
                                              int* __restrict__ cursor,
                                              int* __restrict__ csr_src,
                                              float* __restrict__ csr_nrm)
{
    int e = blockIdx.x * blockDim.x + threadIdx.x;
    if (e < N_EDGES) {
        int s = src[e], d = dst[e];
        float nm = dis[s] * w[e] * dis[d];
        int pos = atomicAdd(cursor + d, 1);
        csr_src[pos] = s;
        csr_nrm[pos] = nm;
    }
}

// ---------------------------------------------------------------------------
// Aggregate BN0(h) over the graph at width 5 (fused BN0 apply).
// ---------------------------------------------------------------------------
__global__ __launch_bounds__(256) void k_agg0(const float* __restrict__ h,
                                              const float* __restrict__ stats,
                                              const float* __restrict__ g0,
                                              const float* __restrict__ be0,
                                              const int* __restrict__ rowptr,
                                              const int* __restrict__ csr_src,
                                              const float* __restrict__ csr_nrm,
                                              const float* __restrict__ dis,
                                              float* __restrict__ agg)
{
    int n = blockIdx.x * blockDim.x + threadIdx.x;
    if (n >= N_NODES) return;
    float sc[D_IN], sh[D_IN];
#pragma unroll
    for (int f = 0; f < D_IN; ++f) {
        float m = stats[f] * (1.0f / N_NODES);
        float var = stats[D_IN + f] * (1.0f / N_NODES) - m * m;
        sc[f] = rsqrtf(var + BN_EPS) * g0[f];
        sh[f] = be0[f] - m * sc[f];
    }
    float dn = dis[n];
    float sl = dn * dn;
    float acc[D_IN];
#pragma unroll
    for (int f = 0; f < D_IN; ++f)
        acc[f] = sl * (h[n * D_IN + f] * sc[f] + sh[f]);
    int e0 = rowptr[n], e1 = rowptr[n + 1];
    for (int e = e0; e < e1; ++e) {
        int s = csr_src[e];
        float nm = csr_nrm[e];
#pragma unroll
        for (int f = 0; f < D_IN; ++f)
            acc[f] += nm * (h[s * D_IN + f] * sc[f] + sh[f]);
    }
#pragma unroll
    for (int f = 0; f < D_IN; ++f)
        agg[n * D_IN + f] = acc[f];
}

// ---------------------------------------------------------------------------
// Layer-1 skinny GEMM: x1 = agg0 @ W1 + b1  (K=5), fused BN1 stats.
// MUST be launched with exactly 512 blocks x 256 threads.
// ---------------------------------------------------------------------------
__global__ __launch_bounds__(256) void k_l1(const float* __restrict__ agg,
                                            const float* __restrict__ W1,
                                            const float* __restrict__ b1,
                                            float* __restrict__ x,
                                            float* __restrict__ stats)
{
    __shared__ float sm_s[256], sm_q[256];
    int t = threadIdx.x;
    int idx0 = blockIdx.x * 256 + t;
    int f = idx0 & (D_H - 1);
    float w[D_IN];
#pragma unroll
    for (int k = 0; k < D_IN; ++k) w[k] = W1[k * D_H + f];
    float b = b1[f];
    float s = 0.f, q = 0.f;
    const int stride = 512 * 256;
    for (int idx = idx0; idx < N_NODES * D_H; idx += stride) {
        int n = idx >> 7;
        const float* a = agg + n * D_IN;
        float v = b;
#pragma unroll
        for (int k = 0; k < D_IN; ++k) v += w[k] * a[k];
        x[idx] = v;
        s += v;
        q += v * v;
    }
    sm_s[t] = s;
    sm_q[t] = q;
    __syncthreads();
    if (t < D_H) {
        atomicAdd(stats + t, sm_s[t] + sm_s[t + D_H]);
        atomicAdd(stats + D_H + t, sm_q[t] + sm_q[t + D_H]);
    }
}

// ---------------------------------------------------------------------------
// BN apply + ReLU, fp32 in -> bf16 out
// ---------------------------------------------------------------------------
__global__ __launch_bounds__(256) void k_bn_relu_bf16(const float* __restrict__ x,
                                                      const float* __restrict__ stats,
                                                      const float* __restrict__ g,
                                                      const float* __restrict__ be,
                                                      unsigned short* __restrict__ y)
{
    int i4 = blockIdx.x * blockDim.x + threadIdx.x;
    if (i4 >= N_NODES * D_H / 4) return;
    int f0 = (i4 & 31) * 4;
    float4 s4 = *(const float4*)(stats + f0);
    float4 q4 = *(const float4*)(stats + D_H + f0);
    float4 g4 = *(const float4*)(g + f0);
    float4 b4 = *(const float4*)(be + f0);
    float4 v = *(const float4*)(x + (size_t)i4 * 4);
    const float inv = 1.0f / N_NODES;
    float m, var, sc, sh;
    float r0, r1, r2, r3;
    m = s4.x * inv; var = q4.x * inv - m * m; sc = rsqrtf(var + BN_EPS) * g4.x; sh = b4.x - m * sc;
    r0 = fmaxf(v.x * sc + sh, 0.f);
    m = s4.y * inv; var = q4.y * inv - m * m; sc = rsqrtf(var + BN_EPS) * g4.y; sh = b4.y - m * sc;
    r1 = fmaxf(v.y * sc + sh, 0.f);
    m = s4.z * inv; var = q4.z * inv - m * m; sc = rsqrtf(var + BN_EPS) * g4.z; sh = b4.z - m * sc;
    r2 = fmaxf(v.z * sc + sh, 0.f);
    m = s4.w * inv; var = q4.w * inv - m * m; sc = rsqrtf(var + BN_EPS) * g4.w; sh = b4.w - m * sc;
    r3 = fmaxf(v.w * sc + sh, 0.f);
    uint2 o;
    o.x = (unsigned)f2bfb(r0) | ((unsigned)f2bfb(r1) << 16);
    o.y = (unsigned)f2bfb(r2) | ((unsigned)f2bfb(r3) << 16);
    *(uint2*)(y + (size_t)i4 * 4) = o;
}

// ---------------------------------------------------------------------------
// 128-wide graph aggregation via CSR, bf16 in -> bf16 out, fp32 accumulate.
// 16 lanes per node row (8 features each), 16 nodes per 256-block.
// ---------------------------------------------------------------------------
__global__ __launch_bounds__(256) void k_agg128(const unsigned short* __restrict__ h,
                                                const int* __restrict__ rowptr,
                                                const int* __restrict__ csr_src,
                                                const float* __restrict__ csr_nrm,
                                                const float* __restrict__ dis,
                                                unsigned short* __restrict__ outb)
{
    int t = threadIdx.x;
    int n = blockIdx.x * 16 + (t >> 4);
    int f0 = (t & 15) * 8;
    if (n >= N_NODES) return;
    float d = dis[n];
    float sl = d * d;
    uint4 hv = *(const uint4*)(h + (size_t)n * D_H + f0);
    float a0 = sl * bflo(hv.x), a1 = sl * bfhi(hv.x);
    float a2 = sl * bflo(hv.y), a3 = sl * bfhi(hv.y);
    float a4 = sl * bflo(hv.z), a5 = sl * bfhi(hv.z);
    float a6 = sl * bflo(hv.w), a7 = sl * bfhi(hv.w);
    int e = rowptr[n], e1 = rowptr[n + 1];
    for (; e + 4 <= e1; e += 4) {
        int s0 = csr_src[e + 0], s1 = csr_src[e + 1];
        int s2 = csr_src[e + 2], s3 = csr_src[e + 3];
        float w0 = csr_nrm[e + 0], w1 = csr_nrm[e + 1];
        float w2 = csr_nrm[e + 2], w3 = csr_nrm[e + 3];
        uint4 v0 = *(const uint4*)(h + (size_t)s0 * D_H + f0);
        uint4 v1 = *(const uint4*)(h + (size_t)s1 * D_H + f0);
        uint4 v2 = *(const uint4*)(h + (size_t)s2 * D_H + f0);
        uint4 v3 = *(const uint4*)(h + (size_t)s3 * D_H + f0);
        a0 += w0 * bflo(v0.x) + w1 * bflo(v1.x) + w2 * bflo(v2.x) + w3 * bflo(v3.x);
        a1 += w0 * bfhi(v0.x) + w1 * bfhi(v1.x) + w2 * bfhi(v2.x) + w3 * bfhi(v3.x);
        a2 += w0 * bflo(v0.y) + w1 * bflo(v1.y) + w2 * bflo(v2.y) + w3 * bflo(v3.y);
        a3 += w0 * bfhi(v0.y) + w1 * bfhi(v1.y) + w2 * bfhi(v2.y) + w3 * bfhi(v3.y);
        a4 += w0 * bflo(v0.z) + w1 * bflo(v1.z) + w2 * bflo(v2.z) + w3 * bflo(v3.z);
        a5 += w0 * bfhi(v0.z) + w1 * bfhi(v1.z) + w2 * bfhi(v2.z) + w3 * bfhi(v3.z);
        a6 += w0 * bflo(v0.w) + w1 * bflo(v1.w) + w2 * bflo(v2.w) + w3 * bflo(v3.w);
        a7 += w0 * bfhi(v0.w) + w1 * bfhi(v1.w) + w2 * bfhi(v2.w) + w3 * bfhi(v3.w);
    }
    for (; e < e1; ++e) {
        int s = csr_src[e];
        float nm = csr_nrm[e];
        uint4 v = *(const uint4*)(h + (size_t)s * D_H + f0);
        a0 += nm * bflo(v.x); a1 += nm * bfhi(v.x);
        a2 += nm * bflo(v.y); a3 += nm * bfhi(v.y);
        a4 += nm * bflo(v.z); a5 += nm * bfhi(v.z);
        a6 += nm * bflo(v.w); a7 += nm * bfhi(v.w);
    }
    uint4 o;
    o.x = (unsigned)f2bfb(a0) | ((unsigned)f2bfb(a1) << 16);
    o.y = (unsigned)f2bfb(a2) | ((unsigned)f2bfb(a3) << 16);
    o.z = (unsigned)f2bfb(a4) | ((unsigned)f2bfb(a5) << 16);
    o.w = (unsigned)f2bfb(a6) | ((unsigned)f2bfb(a7) << 16);
    *(uint4*)(outb + (size_t)n * D_H + f0) = o;
}

// ---------------------------------------------------------------------------
// MFMA GEMM: C[N,128] = A_bf16[N,128] @ W + bias, fused BN stats.
// Bt is W transposed to [n][k] bf16. Block = 4 waves x 16 rows.
// ---------------------------------------------------------------------------
__global__ __launch_bounds__(256) void k_gemm_mf(const unsigned short* __restrict__ A,
                                                 const unsigned short* __restrict__ Bt,
                                                 const float* __restrict__ bias,
                                                 float* __restrict__ C,
                                                 float* __restrict__ stats)
{
    __shared__ float sm_s[D_H], sm_q[D_H];
    int t = threadIdx.x;
    if (t < D_H) { sm_s[t] = 0.f; sm_q[t] = 0.f; }
    __syncthreads();
    int wave = t >> 6, lane = t & 63;
    int m = lane & 15, quad = lane >> 4;
    int r0 = blockIdx.x * 64 + wave * 16;
    int arow = r0 + m < N_NODES ? r0 + m : N_NODES - 1;
    const bf16x8* ap = (const bf16x8*)(A + (size_t)arow * D_H + quad * 8);
    bf16x8 af[4];
#pragma unroll
    for (int ks = 0; ks < 4; ++ks) af[ks] = ap[ks * 4];   // +32 k per step
    f32x4 acc[8];
#pragma unroll
    for (int ct = 0; ct < 8; ++ct) acc[ct] = (f32x4)(0.f);
#pragma unroll
    for (int ks = 0; ks < 4; ++ks) {
#pragma unroll
        for (int ct = 0; ct < 8; ++ct) {
            const bf16x8* bp = (const bf16x8*)(Bt + (size_t)(ct * 16 + m) * D_H + quad * 8);
            acc[ct] = __builtin_amdgcn_mfma_f32_16x16x32_bf16(af[ks], bp[ks * 4], acc[ct], 0, 0, 0);
        }
    }
#pragma unroll
    for (int ct = 0; ct < 8; ++ct) {
        int col = ct * 16 + m;
        float bv = bias[col];
        float s = 0.f, q = 0.f;
#pragma unroll
        for (int r = 0; r < 4; ++r) {
            int rr = r0 + quad * 4 + r;
            if (rr < N_NODES) {
                float v = acc[ct][r] + bv;
                C[(size_t)rr * D_H + col] = v;
                s += v; q += v * v;
            }
        }
        atomicAdd(&sm_s[col], s);
        atomicAdd(&sm_q[col], q);
    }
    __syncthreads();
    if (t < D_H) {
        atomicAdd(stats + t, sm_s[t]);
        atomicAdd(stats + D_H + t, sm_q[t]);
    }
}

// ---------------------------------------------------------------------------
// MFMA dual GEMM: mu = A@Wmu+bmu -> out, ls = A@Wls+bls -> out + N*128.
// ---------------------------------------------------------------------------
__global__ __launch_bounds__(256) void k_gemm_out_mf(const unsigned short* __restrict__ A,
                                                     const unsigned short* __restrict__ Btmu,
                                                     const float* __restrict__ bmu,
                                                     const unsigned short* __restrict__ Btls,
                                                     const float* __restrict__ bls,
                                                     float* __restrict__ out)
{
    int t = threadIdx.x;
    int wave = t >> 6, lane = t & 63;
    int m = lane & 15, quad = lane >> 4;
    int r0 = blockIdx.x * 64 + wave * 16;
    int arow = r0 + m < N_NODES ? r0 + m : N_NODES - 1;
    const bf16x8* ap = (const bf16x8*)(A + (size_t)arow * D_H + quad * 8);
    bf16x8 af[4];
#pragma unroll
    for (int ks = 0; ks < 4; ++ks) af[ks] = ap[ks * 4];
#pragma unroll
    for (int half = 0; half < 2; ++half) {
        const unsigned short* Bt = half ? Btls : Btmu;
        const float* bias = half ? bls : bmu;
        float* C = out + (half ? (size_t)N_NODES * D_H : 0);
        f32x4 acc[8];
#pragma unroll
        for (int ct = 0; ct < 8; ++ct) acc[ct] = (f32x4)(0.f);
#pragma unroll
        for (int ks = 0; ks < 4; ++ks) {
#pragma unroll
            for (int ct = 0; ct < 8; ++ct) {
                const bf16x8* bp = (const bf16x8*)(Bt + (size_t)(ct * 16 + m) * D_H + quad * 8);
                acc[ct] = __builtin_amdgcn_mfma_f32_16x16x32_bf16(af[ks], bp[ks * 4], acc[ct], 0, 0, 0);
            }
        }
#pragma unroll
        for (int ct = 0; ct < 8; ++ct) {
            int col = ct * 16 + m;
            float bv = bias[col];
#pragma unroll
            for (int r = 0; r < 4; ++r) {
                int rr = r0 + quad * 4 + r;
                if (rr < N_NODES)
                    C[(size_t)rr * D_H + col] = acc[ct][r] + bv;
            }
        }
    }
}

// ---------------------------------------------------------------------------
extern "C" void kernel_launch(void* const* d_in, const int* in_sizes, int n_in,
                              void* d_out, int out_size, void* d_ws, size_t ws_size,
                              hipStream_t stream)
{
    const float* h   = (const float*)d_in[0];
    const int*   eidx = (const int*)d_in[1];
    const float* ew  = (const float*)d_in[2];
    const float* g0  = (const float*)d_in[3];
    const float* be0 = (const float*)d_in[4];
    const float* W1  = (const float*)d_in[5];
    const float* b1  = (const float*)d_in[6];
    const float* g1  = (const float*)d_in[7];
    const float* be1 = (const float*)d_in[8];
    const float* W2  = (const float*)d_in[9];
    const float* b2  = (const float*)d_in[10];
    const float* g2  = (const float*)d_in[11];
    const float* be2 = (const float*)d_in[12];
    const float* Wmu = (const float*)d_in[13];
    const float* bmu = (const float*)d_in[14];
    const float* Wls = (const float*)d_in[15];
    const float* bls = (const float*)d_in[16];
    const int* srcv = eidx;
    const int* dstv = eidx + N_EDGES;
    float* out = (float*)d_out;

    char* ws = (char*)d_ws;
    size_t off = 0;
    auto alloc = [&](size_t bytes) -> char* {
        char* p = ws + off;
        off += (bytes + 255) & ~(size_t)255;
        return p;
    };
    float* stats0  = (float*)alloc(16 * 4);
    float* stats1  = (float*)alloc(256 * 4);
    float* stats2  = (float*)alloc(256 * 4);
    float* deg     = (float*)alloc(N_NODES * 4);
    int*   rowptr  = (int*)  alloc((N_NODES + 1) * 4);
    size_t zero_bytes = off;                 // everything above must start at 0
    float* dis     = (float*)alloc(N_NODES * 4);
    int*   cursor  = (int*)  alloc(N_NODES * 4);
    int*   blocksums = (int*)alloc(256 * 4);
    int*   csr_src = (int*)  alloc(N_EDGES * 4);
    float* csr_nrm = (float*)alloc(N_EDGES * 4);
    float* agg0    = (float*)alloc(N_NODES * D_IN * 4);
    float* bufA    = (float*)alloc((size_t)N_NODES * D_H * 4);           // fp32 pre-BN
    unsigned short* bufAh = (unsigned short*)alloc((size_t)N_NODES * D_H * 2);  // bf16 post-BN
    unsigned short* bufBh = (unsigned short*)alloc((size_t)N_NODES * D_H * 2);  // bf16 agg
    unsigned short* Wt2   = (unsigned short*)alloc(D_H * D_H * 2);
    unsigned short* Wtmu  = (unsigned short*)alloc(D_H * D_H * 2);
    unsigned short* Wtls  = (unsigned short*)alloc(D_H * D_H * 2);
    (void)ws_size; (void)in_sizes; (void)n_in; (void)out_size;

    hipMemsetAsync(d_ws, 0, zero_bytes, stream);

    k_wprep<<<192, 256, 0, stream>>>(W2, Wmu, Wls, Wt2, Wtmu, Wtls);
    k_bn0_stats<<<(N_NODES + 255) / 256, 256, 0, stream>>>(h, stats0);
    k_deg_count<<<(N_EDGES + 255) / 256, 256, 0, stream>>>(dstv, ew, deg, rowptr);
    k_scan1<<<SCAN_BLOCKS, 256, 0, stream>>>(rowptr, deg, dis, blocksums);
    k_scan2<<<1, 256, 0, stream>>>(blocksums, rowptr);
    k_scan3<<<SCAN_BLOCKS, 256, 0, stream>>>(rowptr, cursor, blocksums);
    k_fill<<<(N_EDGES + 255) / 256, 256, 0, stream>>>(srcv, dstv, ew, dis, cursor,
                                                      csr_src, csr_nrm);
    k_agg0<<<(N_NODES + 255) / 256, 256, 0, stream>>>(h, stats0, g0, be0, rowptr,
                                                      csr_src, csr_nrm, dis, agg0);
    k_l1<<<512, 256, 0, stream>>>(agg0, W1, b1, bufA, stats1);
    k_bn_relu_bf16<<<(N_NODES * D_H / 4 + 255) / 256, 256, 0, stream>>>(bufA, stats1, g1, be1, bufAh);
    k_agg128<<<(N_NODES + 15) / 16, 256, 0, stream>>>(bufAh, rowptr, csr_src, csr_nrm,
                                                      dis, bufBh);
    k_gemm_mf<<<(N_NODES + 63) / 64, 256, 0, stream>>>(bufBh, Wt2, b2, bufA, stats2);
    k_bn_relu_bf16<<<(N_NODES * D_H / 4 + 255) / 256, 256, 0, stream>>>(bufA, stats2, g2, be2, bufAh);
    k_gemm_out_mf<<<(N_NODES + 63) / 64, 256, 0, stream>>>(bufAh, Wtmu, bmu, Wtls, bls, out);
}

// Round 5
// 350.774 us; speedup vs baseline: 1.9021x; 1.1031x over previous
//
#include <hip/hip_runtime.h>

#define N_NODES 50000
#define N_EDGES 600000
#define D_IN 5
#define D_H 128
#define BN_EPS 1e-5f
#define SCAN_BLOCKS ((N_NODES + 255) / 256)   // 196
#define FIX_SCALE 16777216.0f                  // 2^24
#define FIX_INV   (1.0f / 16777216.0f)

typedef __bf16 bf16x8 __attribute__((ext_vector_type(8)));
typedef float  f32x4  __attribute__((ext_vector_type(4)));

__device__ inline unsigned short f2bfb(float f) {          // fp32 -> bf16 bits, RNE
    unsigned u = __builtin_bit_cast(unsigned, f);
    unsigned r = u + 0x7fffu + ((u >> 16) & 1u);
    return (unsigned short)(r >> 16);
}
__device__ inline float bflo(unsigned u) { return __builtin_bit_cast(float, u << 16); }
__device__ inline float bfhi(unsigned u) { return __builtin_bit_cast(float, u & 0xffff0000u); }

// ---------------------------------------------------------------------------
// Weight prep: W[k][n] fp32 -> Wt[n][k] bf16, for W2 / Wmu / Wls
// ---------------------------------------------------------------------------
__global__ __launch_bounds__(256) void k_wprep(const float* __restrict__ W2,
                                               const float* __restrict__ Wmu,
                                               const float* __restrict__ Wls,
                                               unsigned short* __restrict__ T2,
                                               unsigned short* __restrict__ Tmu,
                                               unsigned short* __restrict__ Tls)
{
    int mat = blockIdx.x >> 6;
    int idx = (blockIdx.x & 63) * 256 + threadIdx.x;   // < 16384
    const float* W = (mat == 0) ? W2 : (mat == 1) ? Wmu : Wls;
    unsigned short* T = (mat == 0) ? T2 : (mat == 1) ? Tmu : Tls;
    int k = idx >> 7, n = idx & 127;
    T[n * D_H + k] = f2bfb(W[idx]);
}

// ---------------------------------------------------------------------------
// BN0 statistics: per-feature sum & sumsq over nodes (5 features)
// ---------------------------------------------------------------------------
__global__ __launch_bounds__(256) void k_bn0_stats(const float* __restrict__ h,
                                                   float* __restrict__ stats)
{
    __shared__ float ss[D_IN], sq[D_IN];
    int t = threadIdx.x;
    if (t < D_IN) { ss[t] = 0.f; sq[t] = 0.f; }
    __syncthreads();
    int node = blockIdx.x * blockDim.x + t;
    float v[D_IN];
#pragma unroll
    for (int f = 0; f < D_IN; ++f)
        v[f] = (node < N_NODES) ? h[node * D_IN + f] : 0.f;
    int lane = t & 63;
#pragma unroll
    for (int f = 0; f < D_IN; ++f) {
        float s = v[f], q = v[f] * v[f];
        for (int off = 32; off > 0; off >>= 1) {
            s += __shfl_down(s, off);
            q += __shfl_down(q, off);
        }
        if (lane == 0) { atomicAdd(&ss[f], s); atomicAdd(&sq[f], q); }
    }
    __syncthreads();
    if (t < D_IN) {
        atomicAdd(&stats[t], ss[t]);
        atomicAdd(&stats[D_IN + t], sq[t]);
    }
}

// ---------------------------------------------------------------------------
// Per-edge: ONE u64 atomic per edge. bits[63:40] = count, bits[39:0] =
// weighted degree in 16.24 fixed point (max deg ~64 << 2^16, no carry-out).
// ---------------------------------------------------------------------------
__global__ __launch_bounds__(256) void k_deg_count(const int* __restrict__ dst,
                                                   const float* __restrict__ w,
                                                   unsigned long long* __restrict__ degcnt)
{
    int e = blockIdx.x * blockDim.x + threadIdx.x;
    if (e < N_EDGES) {
        int d = dst[e];
        unsigned long long fx = (unsigned long long)(w[e] * FIX_SCALE + 0.5f);
        atomicAdd(degcnt + d, (1ull << 40) | fx);
    }
}

// ---------------------------------------------------------------------------
// Scan pass 1: per-block sum of counts -> blocksums; also dis = rsqrt(deg+1)
// ---------------------------------------------------------------------------
__global__ __launch_bounds__(256) void k_scan1(const unsigned long long* __restrict__ degcnt,
                                               float* __restrict__ dis,
                                               int* __restrict__ blocksums)
{
    __shared__ int sm[256];
    int t = threadIdx.x;
    int i = blockIdx.x * 256 + t;
    int c = 0;
    if (i < N_NODES) {
        unsigned long long v = degcnt[i];
        c = (int)(v >> 40);
        float deg = (float)(v & ((1ull << 40) - 1)) * FIX_INV;
        dis[i] = rsqrtf(deg + 1.0f);
    }
    sm[t] = c;
    __syncthreads();
    for (int off = 128; off > 0; off >>= 1) {
        if (t < off) sm[t] += sm[t + off];
        __syncthreads();
    }
    if (t == 0) blocksums[blockIdx.x] = sm[0];
}

// ---------------------------------------------------------------------------
// Scan pass 2: single block exclusive scan of block sums (196 <= 256)
// ---------------------------------------------------------------------------
__global__ __launch_bounds__(256) void k_scan2(int* __restrict__ blocksums,
                                               int* __restrict__ rowptr)
{
    __shared__ int sm[256];
    int t = threadIdx.x;
    int c = (t < SCAN_BLOCKS) ? blocksums[t] : 0;
    sm[t] = c;
    __syncthreads();
    for (int off = 1; off < 256; off <<= 1) {
        int v = (t >= off) ? sm[t - off] : 0;
        __syncthreads();
        sm[t] += v;
        __syncthreads();
    }
    if (t < SCAN_BLOCKS) blocksums[t] = sm[t] - c;
    if (t == 255) rowptr[N_NODES] = sm[255];
}

// ---------------------------------------------------------------------------
// Scan pass 3: per-block exclusive scan + block offset -> rowptr & cursor
// ---------------------------------------------------------------------------
__global__ __launch_bounds__(256) void k_scan3(const unsigned long long* __restrict__ degcnt,
                                               int* __restrict__ rowptr,
                                               int* __restrict__ cursor,
                                               const int* __restrict__ blocksums)
{
    __shared__ int sm[256];
    int t = threadIdx.x;
    int i = blockIdx.x * 256 + t;
    int c = (i < N_NODES) ? (int)(degcnt[i] >> 40) : 0;
    sm[t] = c;
    __syncthreads();
    for (int off = 1; off < 256; off <<= 1) {
        int v = (t >= off) ? sm[t - off] : 0;
        __syncthreads();
        sm[t] += v;
        __syncthreads();
    }
    if (i < N_NODES) {
        int pos = blocksums[blockIdx.x] + sm[t] - c;
        rowptr[i] = pos;
        cursor[i] = pos;
    }
}

// ---------------------------------------------------------------------------
// Fill CSR: packed {src, norm-bits} int2 -> single 8 B store per edge
// ---------------------------------------------------------------------------
__global__ __launch_bounds__(256) void k_fill(const int* __restrict__ src,
                                              const int* __restrict__ dst,
                                              const float* __restrict__ w,
                                              const float* __restrict__ dis,
                                              int* __restrict__ cursor,
                                              int2* __restrict__ csr)
{
    int e = blockIdx.x * blockDim.x + threadIdx.x;
    if (e < N_EDGES) {
        int s = src[e], d = dst[e];
        float nm = dis[s] * w[e] * dis[d];
        int pos = atomicAdd(cursor + d, 1);
        int2 pk;
        pk.x = s;
        pk.y = __builtin_bit_cast(int, nm);
        csr[pos] = pk;
    }
}

// ---------------------------------------------------------------------------
// Aggregate BN0(h) over the graph at width 5 (fused BN0 apply).
// ---------------------------------------------------------------------------
__global__ __launch_bounds__(256) void k_agg0(const float* __restrict__ h,
                                              const float* __restrict__ stats,
                                              const float* __restrict__ g0,
                                              const float* __restrict__ be0,
                                              const int* __restrict__ rowptr,
                                              const int2* __restrict__ csr,
                                              const float* __restrict__ dis,
                                              float* __restrict__ agg)
{
    int n = blockIdx.x * blockDim.x + threadIdx.x;
    if (n >= N_NODES) return;
    float sc[D_IN], sh[D_IN];
#pragma unroll
    for (int f = 0; f < D_IN; ++f) {
        float m = stats[f] * (1.0f / N_NODES);
        float var = stats[D_IN + f] * (1.0f / N_NODES) - m * m;
        sc[f] = rsqrtf(var + BN_EPS) * g0[f];
        sh[f] = be0[f] - m * sc[f];
    }
    float dn = dis[n];
    float sl = dn * dn;
    float acc[D_IN];
#pragma unroll
    for (int f = 0; f < D_IN; ++f)
        acc[f] = sl * (h[n * D_IN + f] * sc[f] + sh[f]);
    int e0 = rowptr[n], e1 = rowptr[n + 1];
    for (int e = e0; e < e1; ++e) {
        int2 pk = csr[e];
        int s = pk.x;
        float nm = __builtin_bit_cast(float, pk.y);
#pragma unroll
        for (int f = 0; f < D_IN; ++f)
            acc[f] += nm * (h[s * D_IN + f] * sc[f] + sh[f]);
    }
#pragma unroll
    for (int f = 0; f < D_IN; ++f)
        agg[n * D_IN + f] = acc[f];
}

// ---------------------------------------------------------------------------
// Layer-1 skinny GEMM: x1 = agg0 @ W1 + b1  (K=5), fused BN1 stats.
// MUST be launched with exactly 512 blocks x 256 threads.
// ---------------------------------------------------------------------------
__global__ __launch_bounds__(256) void k_l1(const float* __restrict__ agg,
                                            const float* __restrict__ W1,
                                            const float* __restrict__ b1,
                                            float* __restrict__ x,
                                            float* __restrict__ stats)
{
    __shared__ float sm_s[256], sm_q[256];
    int t = threadIdx.x;
    int idx0 = blockIdx.x * 256 + t;
    int f = idx0 & (D_H - 1);
    float w[D_IN];
#pragma unroll
    for (int k = 0; k < D_IN; ++k) w[k] = W1[k * D_H + f];
    float b = b1[f];
    float s = 0.f, q = 0.f;
    const int stride = 512 * 256;
    for (int idx = idx0; idx < N_NODES * D_H; idx += stride) {
        int n = idx >> 7;
        const float* a = agg + n * D_IN;
        float v = b;
#pragma unroll
        for (int k = 0; k < D_IN; ++k) v += w[k] * a[k];
        x[idx] = v;
        s += v;
        q += v * v;
    }
    sm_s[t] = s;
    sm_q[t] = q;
    __syncthreads();
    if (t < D_H) {
        atomicAdd(stats + t, sm_s[t] + sm_s[t + D_H]);
        atomicAdd(stats + D_H + t, sm_q[t] + sm_q[t + D_H]);
    }
}

// ---------------------------------------------------------------------------
// BN apply + ReLU, fp32 in -> bf16 out
// ---------------------------------------------------------------------------
__global__ __launch_bounds__(256) void k_bn_relu_bf16(const float* __restrict__ x,
                                                      const float* __restrict__ stats,
                                                      const float* __restrict__ g,
                                                      const float* __restrict__ be,
                                                      unsigned short* __restrict__ y)
{
    int i4 = blockIdx.x * blockDim.x + threadIdx.x;
    if (i4 >= N_NODES * D_H / 4) return;
    int f0 = (i4 & 31) * 4;
    float4 s4 = *(const float4*)(stats + f0);
    float4 q4 = *(const float4*)(stats + D_H + f0);
    float4 g4 = *(const float4*)(g + f0);
    float4 b4 = *(const float4*)(be + f0);
    float4 v = *(const float4*)(x + (size_t)i4 * 4);
    const float inv = 1.0f / N_NODES;
    float m, var, sc, sh;
    float r0, r1, r2, r3;
    m = s4.x * inv; var = q4.x * inv - m * m; sc = rsqrtf(var + BN_EPS) * g4.x; sh = b4.x - m * sc;
    r0 = fmaxf(v.x * sc + sh, 0.f);
    m = s4.y * inv; var = q4.y * inv - m * m; sc = rsqrtf(var + BN_EPS) * g4.y; sh = b4.y - m * sc;
    r1 = fmaxf(v.y * sc + sh, 0.f);
    m = s4.z * inv; var = q4.z * inv - m * m; sc = rsqrtf(var + BN_EPS) * g4.z; sh = b4.z - m * sc;
    r2 = fmaxf(v.z * sc + sh, 0.f);
    m = s4.w * inv; var = q4.w * inv - m * m; sc = rsqrtf(var + BN_EPS) * g4.w; sh = b4.w - m * sc;
    r3 = fmaxf(v.w * sc + sh, 0.f);
    uint2 o;
    o.x = (unsigned)f2bfb(r0) | ((unsigned)f2bfb(r1) << 16);
    o.y = (unsigned)f2bfb(r2) | ((unsigned)f2bfb(r3) << 16);
    *(uint2*)(y + (size_t)i4 * 4) = o;
}

// ---------------------------------------------------------------------------
// 128-wide graph aggregation via CSR, bf16 in -> bf16 out, fp32 accumulate.
// 16 lanes per node row (8 features each), 16 nodes per 256-block.
// ---------------------------------------------------------------------------
__global__ __launch_bounds__(256) void k_agg128(const unsigned short* __restrict__ h,
                                                const int* __restrict__ rowptr,
                                                const int2* __restrict__ csr,
                                                const float* __restrict__ dis,
                                                unsigned short* __restrict__ outb)
{
    int t = threadIdx.x;
    int n = blockIdx.x * 16 + (t >> 4);
    int f0 = (t & 15) * 8;
    if (n >= N_NODES) return;
    float d = dis[n];
    float sl = d * d;
    uint4 hv = *(const uint4*)(h + (size_t)n * D_H + f0);
    float a0 = sl * bflo(hv.x), a1 = sl * bfhi(hv.x);
    float a2 = sl * bflo(hv.y), a3 = sl * bfhi(hv.y);
    float a4 = sl * bflo(hv.z), a5 = sl * bfhi(hv.z);
    float a6 = sl * bflo(hv.w), a7 = sl * bfhi(hv.w);
    int e = rowptr[n], e1 = rowptr[n + 1];
    for (; e + 4 <= e1; e += 4) {
        int2 p0 = csr[e + 0], p1 = csr[e + 1], p2 = csr[e + 2], p3 = csr[e + 3];
        float w0 = __builtin_bit_cast(float, p0.y);
        float w1 = __builtin_bit_cast(float, p1.y);
        float w2 = __builtin_bit_cast(float, p2.y);
        float w3 = __builtin_bit_cast(float, p3.y);
        uint4 v0 = *(const uint4*)(h + (size_t)p0.x * D_H + f0);
        uint4 v1 = *(const uint4*)(h + (size_t)p1.x * D_H + f0);
        uint4 v2 = *(const uint4*)(h + (size_t)p2.x * D_H + f0);
        uint4 v3 = *(const uint4*)(h + (size_t)p3.x * D_H + f0);
        a0 += w0 * bflo(v0.x) + w1 * bflo(v1.x) + w2 * bflo(v2.x) + w3 * bflo(v3.x);
        a1 += w0 * bfhi(v0.x) + w1 * bfhi(v1.x) + w2 * bfhi(v2.x) + w3 * bfhi(v3.x);
        a2 += w0 * bflo(v0.y) + w1 * bflo(v1.y) + w2 * bflo(v2.y) + w3 * bflo(v3.y);
        a3 += w0 * bfhi(v0.y) + w1 * bfhi(v1.y) + w2 * bfhi(v2.y) + w3 * bfhi(v3.y);
        a4 += w0 * bflo(v0.z) + w1 * bflo(v1.z) + w2 * bflo(v2.z) + w3 * bflo(v3.z);
        a5 += w0 * bfhi(v0.z) + w1 * bfhi(v1.z) + w2 * bfhi(v2.z) + w3 * bfhi(v3.z);
        a6 += w0 * bflo(v0.w) + w1 * bflo(v1.w) + w2 * bflo(v2.w) + w3 * bflo(v3.w);
        a7 += w0 * bfhi(v0.w) + w1 * bfhi(v1.w) + w2 * bfhi(v2.w) + w3 * bfhi(v3.w);
    }
    for (; e < e1; ++e) {
        int2 pk = csr[e];
        float nm = __builtin_bit_cast(float, pk.y);
        uint4 v = *(const uint4*)(h + (size_t)pk.x * D_H + f0);
        a0 += nm * bflo(v.x); a1 += nm * bfhi(v.x);
        a2 += nm * bflo(v.y); a3 += nm * bfhi(v.y);
        a4 += nm * bflo(v.z); a5 += nm * bfhi(v.z);
        a6 += nm * bflo(v.w); a7 += nm * bfhi(v.w);
    }
    uint4 o;
    o.x = (unsigned)f2bfb(a0) | ((unsigned)f2bfb(a1) << 16);
    o.y = (unsigned)f2bfb(a2) | ((unsigned)f2bfb(a3) << 16);
    o.z = (unsigned)f2bfb(a4) | ((unsigned)f2bfb(a5) << 16);
    o.w = (unsigned)f2bfb(a6) | ((unsigned)f2bfb(a7) << 16);
    *(uint4*)(outb + (size_t)n * D_H + f0) = o;
}

// ---------------------------------------------------------------------------
// MFMA GEMM: C[N,128] = A_bf16[N,128] @ W + bias, fused BN stats.
// ---------------------------------------------------------------------------
__global__ __launch_bounds__(256) void k_gemm_mf(const unsigned short* __restrict__ A,
                                                 const unsigned short* __restrict__ Bt,
                                                 const float* __restrict__ bias,
                                                 float* __restrict__ C,
                                                 float* __restrict__ stats)
{
    __shared__ float sm_s[D_H], sm_q[D_H];
    int t = threadIdx.x;
    if (t < D_H) { sm_s[t] = 0.f; sm_q[t] = 0.f; }
    __syncthreads();
    int wave = t >> 6, lane = t & 63;
    int m = lane & 15, quad = lane >> 4;
    int r0 = blockIdx.x * 64 + wave * 16;
    int arow = r0 + m < N_NODES ? r0 + m : N_NODES - 1;
    const bf16x8* ap = (const bf16x8*)(A + (size_t)arow * D_H + quad * 8);
    bf16x8 af[4];
#pragma unroll
    for (int ks = 0; ks < 4; ++ks) af[ks] = ap[ks * 4];
    f32x4 acc[8];
#pragma unroll
    for (int ct = 0; ct < 8; ++ct) acc[ct] = (f32x4)(0.f);
#pragma unroll
    for (int ks = 0; ks < 4; ++ks) {
#pragma unroll
        for (int ct = 0; ct < 8; ++ct) {
            const bf16x8* bp = (const bf16x8*)(Bt + (size_t)(ct * 16 + m) * D_H + quad * 8);
            acc[ct] = __builtin_amdgcn_mfma_f32_16x16x32_bf16(af[ks], bp[ks * 4], acc[ct], 0, 0, 0);
        }
    }
#pragma unroll
    for (int ct = 0; ct < 8; ++ct) {
        int col = ct * 16 + m;
        float bv = bias[col];
        float s = 0.f, q = 0.f;
#pragma unroll
        for (int r = 0; r < 4; ++r) {
            int rr = r0 + quad * 4 + r;
            if (rr < N_NODES) {
                float v = acc[ct][r] + bv;
                C[(size_t)rr * D_H + col] = v;
                s += v; q += v * v;
            }
        }
        atomicAdd(&sm_s[col], s);
        atomicAdd(&sm_q[col], q);
    }
    __syncthreads();
    if (t < D_H) {
        atomicAdd(stats + t, sm_s[t]);
        atomicAdd(stats + D_H + t, sm_q[t]);
    }
}

// ---------------------------------------------------------------------------
// MFMA dual GEMM: mu = A@Wmu+bmu -> out, ls = A@Wls+bls -> out + N*128.
// ---------------------------------------------------------------------------
__global__ __launch_bounds__(256) void k_gemm_out_mf(const unsigned short* __restrict__ A,
                                                     const unsigned short* __restrict__ Btmu,
                                                     const float* __restrict__ bmu,
                                                     const unsigned short* __restrict__ Btls,
                                                     const float* __restrict__ bls,
                                                     float* __restrict__ out)
{
    int t = threadIdx.x;
    int wave = t >> 6, lane = t & 63;
    int m = lane & 15, quad = lane >> 4;
    int r0 = blockIdx.x * 64 + wave * 16;
    int arow = r0 + m < N_NODES ? r0 + m : N_NODES - 1;
    const bf16x8* ap = (const bf16x8*)(A + (size_t)arow * D_H + quad * 8);
    bf16x8 af[4];
#pragma unroll
    for (int ks = 0; ks < 4; ++ks) af[ks] = ap[ks * 4];
#pragma unroll
    for (int half = 0; half < 2; ++half) {
        const unsigned short* Bt = half ? Btls : Btmu;
        const float* bias = half ? bls : bmu;
        float* C = out + (half ? (size_t)N_NODES * D_H : 0);
        f32x4 acc[8];
#pragma unroll
        for (int ct = 0; ct < 8; ++ct) acc[ct] = (f32x4)(0.f);
#pragma unroll
        for (int ks = 0; ks < 4; ++ks) {
#pragma unroll
            for (int ct = 0; ct < 8; ++ct) {
                const bf16x8* bp = (const bf16x8*)(Bt + (size_t)(ct * 16 + m) * D_H + quad * 8);
                acc[ct] = __builtin_amdgcn_mfma_f32_16x16x32_bf16(af[ks], bp[ks * 4], acc[ct], 0, 0, 0);
            }
        }
#pragma unroll
        for (int ct = 0; ct < 8; ++ct) {
            int col = ct * 16 + m;
            float bv = bias[col];
#pragma unroll
            for (int r = 0; r < 4; ++r) {
                int rr = r0 + quad * 4 + r;
                if (rr < N_NODES)
                    C[(size_t)rr * D_H + col] = acc[ct][r] + bv;
            }
        }
    }
}

// ---------------------------------------------------------------------------
extern "C" void kernel_launch(void* const* d_in, const int* in_sizes, int n_in,
                              void* d_out, int out_size, void* d_ws, size_t ws_size,
                              hipStream_t stream)
{
    const float* h   = (const float*)d_in[0];
    const int*   eidx = (const int*)d_in[1];
    const float* ew  = (const float*)d_in[2];
    const float* g0  = (const float*)d_in[3];
    const float* be0 = (const float*)d_in[4];
    const float* W1  = (const float*)d_in[5];
    const float* b1  = (const float*)d_in[6];
    const float* g1  = (const float*)d_in[7];
    const float* be1 = (const float*)d_in[8];
    const float* W2  = (const float*)d_in[9];
    const float* b2  = (const float*)d_in[10];
    const float* g2  = (const float*)d_in[11];
    const float* be2 = (const float*)d_in[12];
    const float* Wmu = (const float*)d_in[13];
    const float* bmu = (const float*)d_in[14];
    const float* Wls = (const float*)d_in[15];
    const float* bls = (const float*)d_in[16];
    const int* srcv = eidx;
    const int* dstv = eidx + N_EDGES;
    float* out = (float*)d_out;

    char* ws = (char*)d_ws;
    size_t off = 0;
    auto alloc = [&](size_t bytes) -> char* {
        char* p = ws + off;
        off += (bytes + 255) & ~(size_t)255;
        return p;
    };
    float* stats0  = (float*)alloc(16 * 4);
    float* stats1  = (float*)alloc(256 * 4);
    float* stats2  = (float*)alloc(256 * 4);
    unsigned long long* degcnt = (unsigned long long*)alloc(N_NODES * 8);
    size_t zero_bytes = off;                 // everything above must start at 0
    int*   rowptr  = (int*)  alloc((N_NODES + 1) * 4);
    float* dis     = (float*)alloc(N_NODES * 4);
    int*   cursor  = (int*)  alloc(N_NODES * 4);
    int*   blocksums = (int*)alloc(256 * 4);
    int2*  csr     = (int2*) alloc((size_t)N_EDGES * 8);
    float* agg0    = (float*)alloc(N_NODES * D_IN * 4);
    float* bufA    = (float*)alloc((size_t)N_NODES * D_H * 4);           // fp32 pre-BN
    unsigned short* bufAh = (unsigned short*)alloc((size_t)N_NODES * D_H * 2);  // bf16 post-BN
    unsigned short* bufBh = (unsigned short*)alloc((size_t)N_NODES * D_H * 2);  // bf16 agg
    unsigned short* Wt2   = (unsigned short*)alloc(D_H * D_H * 2);
    unsigned short* Wtmu  = (unsigned short*)alloc(D_H * D_H * 2);
    unsigned short* Wtls  = (unsigned short*)alloc(D_H * D_H * 2);
    (void)ws_size; (void)in_sizes; (void)n_in; (void)out_size;

    hipMemsetAsync(d_ws, 0, zero_bytes, stream);

    k_wprep<<<192, 256, 0, stream>>>(W2, Wmu, Wls, Wt2, Wtmu, Wtls);
    k_bn0_stats<<<(N_NODES + 255) / 256, 256, 0, stream>>>(h, stats0);
    k_deg_count<<<(N_EDGES + 255) / 256, 256, 0, stream>>>(dstv, ew, degcnt);
    k_scan1<<<SCAN_BLOCKS, 256, 0, stream>>>(degcnt, dis, blocksums);
    k_scan2<<<1, 256, 0, stream>>>(blocksums, rowptr);
    k_scan3<<<SCAN_BLOCKS, 256, 0, stream>>>(degcnt, rowptr, cursor, blocksums);
    k_fill<<<(N_EDGES + 255) / 256, 256, 0, stream>>>(srcv, dstv, ew, dis, cursor, csr);
    k_agg0<<<(N_NODES + 255) / 256, 256, 0, stream>>>(h, stats0, g0, be0, rowptr,
                                                      csr, dis, agg0);
    k_l1<<<512, 256, 0, stream>>>(agg0, W1, b1, bufA, stats1);
    k_bn_relu_bf16<<<(N_NODES * D_H / 4 + 255) / 256, 256, 0, stream>>>(bufA, stats1, g1, be1, bufAh);
    k_agg128<<<(N_NODES + 15) / 16, 256, 0, stream>>>(bufAh, rowptr, csr, dis, bufBh);
    k_gemm_mf<<<(N_NODES + 63) / 64, 256, 0, stream>>>(bufBh, Wt2, b2, bufA, stats2);
    k_bn_relu_bf16<<<(N_NODES * D_H / 4 + 255) / 256, 256, 0, stream>>>(bufA, stats2, g2, be2, bufAh);
    k_gemm_out_mf<<<(N_NODES + 63) / 64, 256, 0, stream>>>(bufAh, Wtmu, bmu, Wtls, bls, out);
}

// Round 6
// 325.659 us; speedup vs baseline: 2.0488x; 1.0771x over previous
//
#include <hip/hip_runtime.h>

#define N_NODES 50000
#define N_EDGES 600000
#define D_IN 5
#define D_H 128
#define BN_EPS 1e-5f
#define SCAN_BLOCKS ((N_NODES + 255) / 256)   // 196
#define FIX_SCALE 16777216.0f                  // 2^24
#define FIX_INV   (1.0f / 16777216.0f)

typedef __bf16 bf16x8 __attribute__((ext_vector_type(8)));
typedef float  f32x4  __attribute__((ext_vector_type(4)));

__device__ inline unsigned short f2bfb(float f) {          // fp32 -> bf16 bits, RNE
    unsigned u = __builtin_bit_cast(unsigned, f);
    unsigned r = u + 0x7fffu + ((u >> 16) & 1u);
    return (unsigned short)(r >> 16);
}
__device__ inline float bflo(unsigned u) { return __builtin_bit_cast(float, u << 16); }
__device__ inline float bfhi(unsigned u) { return __builtin_bit_cast(float, u & 0xffff0000u); }

// ---------------------------------------------------------------------------
// Stage Bt[128][128] bf16 (row-major, 256 B rows) into LDS in fragment-major
// order: frag fid = ct*4+ks occupies 1 KB; lane l's 16 B at fid*1024 + l*16.
// Lane l of frag fid holds Bt[row = (fid>>2)*16 + (l&15)]
//                            [bytes (l>>4)*16 + (fid&3)*64 ...+16]
// ---------------------------------------------------------------------------
__device__ inline void stage_b(const unsigned short* __restrict__ Bt,
                               uint4* __restrict__ lds, int t)
{
#pragma unroll
    for (int i = 0; i < 8; ++i) {
        int slot = i * 256 + t;          // 0..2047
        int fid = slot >> 6;
        int l = slot & 63;
        int row = (fid >> 2) * 16 + (l & 15);
        int boff = ((l >> 4) * 16 + (fid & 3) * 64) >> 1;   // in shorts
        lds[slot] = *(const uint4*)(Bt + row * D_H + boff);
    }
}

// ---------------------------------------------------------------------------
// Weight prep: W[k][n] fp32 -> Wt[n][k] bf16, for W2 / Wmu / Wls
// ---------------------------------------------------------------------------
__global__ __launch_bounds__(256) void k_wprep(const float* __restrict__ W2,
                                               const float* __restrict__ Wmu,
                                               const float* __restrict__ Wls,
                                               unsigned short* __restrict__ T2,
                                               unsigned short* __restrict__ Tmu,
                                               unsigned short* __restrict__ Tls)
{
    int mat = blockIdx.x >> 6;
    int idx = (blockIdx.x & 63) * 256 + threadIdx.x;   // < 16384
    const float* W = (mat == 0) ? W2 : (mat == 1) ? Wmu : Wls;
    unsigned short* T = (mat == 0) ? T2 : (mat == 1) ? Tmu : Tls;
    int k = idx >> 7, n = idx & 127;
    T[n * D_H + k] = f2bfb(W[idx]);
}

// ---------------------------------------------------------------------------
// BN0 statistics: per-feature sum & sumsq over nodes (5 features)
// ---------------------------------------------------------------------------
__global__ __launch_bounds__(256) void k_bn0_stats(const float* __restrict__ h,
                                                   float* __restrict__ stats)
{
    __shared__ float ss[D_IN], sq[D_IN];
    int t = threadIdx.x;
    if (t < D_IN) { ss[t] = 0.f; sq[t] = 0.f; }
    __syncthreads();
    int node = blockIdx.x * blockDim.x + t;
    float v[D_IN];
#pragma unroll
    for (int f = 0; f < D_IN; ++f)
        v[f] = (node < N_NODES) ? h[node * D_IN + f] : 0.f;
    int lane = t & 63;
#pragma unroll
    for (int f = 0; f < D_IN; ++f) {
        float s = v[f], q = v[f] * v[f];
        for (int off = 32; off > 0; off >>= 1) {
            s += __shfl_down(s, off);
            q += __shfl_down(q, off);
        }
        if (lane == 0) { atomicAdd(&ss[f], s); atomicAdd(&sq[f], q); }
    }
    __syncthreads();
    if (t < D_IN) {
        atomicAdd(&stats[t], ss[t]);
        atomicAdd(&stats[D_IN + t], sq[t]);
    }
}

// ---------------------------------------------------------------------------
// Per-edge: ONE u64 atomic per edge. bits[63:40] = count, bits[39:0] =
// weighted degree in 16.24 fixed point.
// ---------------------------------------------------------------------------
__global__ __launch_bounds__(256) void k_deg_count(const int* __restrict__ dst,
                                                   const float* __restrict__ w,
                                                   unsigned long long* __restrict__ degcnt)
{
    int e = blockIdx.x * blockDim.x + threadIdx.x;
    if (e < N_EDGES) {
        int d = dst[e];
        unsigned long long fx = (unsigned long long)(w[e] * FIX_SCALE + 0.5f);
        atomicAdd(degcnt + d, (1ull << 40) | fx);
    }
}

// ---------------------------------------------------------------------------
__global__ __launch_bounds__(256) void k_scan1(const unsigned long long* __restrict__ degcnt,
                                               float* __restrict__ dis,
                                               int* __restrict__ blocksums)
{
    __shared__ int sm[256];
    int t = threadIdx.x;
    int i = blockIdx.x * 256 + t;
    int c = 0;
    if (i < N_NODES) {
        unsigned long long v = degcnt[i];
        c = (int)(v >> 40);
        float deg = (float)(v & ((1ull << 40) - 1)) * FIX_INV;
        dis[i] = rsqrtf(deg + 1.0f);
    }
    sm[t] = c;
    __syncthreads();
    for (int off = 128; off > 0; off >>= 1) {
        if (t < off) sm[t] += sm[t + off];
        __syncthreads();
    }
    if (t == 0) blocksums[blockIdx.x] = sm[0];
}

__global__ __launch_bounds__(256) void k_scan2(int* __restrict__ blocksums,
                                               int* __restrict__ rowptr)
{
    __shared__ int sm[256];
    int t = threadIdx.x;
    int c = (t < SCAN_BLOCKS) ? blocksums[t] : 0;
    sm[t] = c;
    __syncthreads();
    for (int off = 1; off < 256; off <<= 1) {
        int v = (t >= off) ? sm[t - off] : 0;
        __syncthreads();
        sm[t] += v;
        __syncthreads();
    }
    if (t < SCAN_BLOCKS) blocksums[t] = sm[t] - c;
    if (t == 255) rowptr[N_NODES] = sm[255];
}

__global__ __launch_bounds__(256) void k_scan3(const unsigned long long* __restrict__ degcnt,
                                               int* __restrict__ rowptr,
                                               int* __restrict__ cursor,
                                               const int* __restrict__ blocksums)
{
    __shared__ int sm[256];
    int t = threadIdx.x;
    int i = blockIdx.x * 256 + t;
    int c = (i < N_NODES) ? (int)(degcnt[i] >> 40) : 0;
    sm[t] = c;
    __syncthreads();
    for (int off = 1; off < 256; off <<= 1) {
        int v = (t >= off) ? sm[t - off] : 0;
        __syncthreads();
        sm[t] += v;
        __syncthreads();
    }
    if (i < N_NODES) {
        int pos = blocksums[blockIdx.x] + sm[t] - c;
        rowptr[i] = pos;
        cursor[i] = pos;
    }
}

// ---------------------------------------------------------------------------
// Fill CSR: packed {src, norm-bits} int2 -> single 8 B store per edge
// ---------------------------------------------------------------------------
__global__ __launch_bounds__(256) void k_fill(const int* __restrict__ src,
                                              const int* __restrict__ dst,
                                              const float* __restrict__ w,
                                              const float* __restrict__ dis,
                                              int* __restrict__ cursor,
                                              int2* __restrict__ csr)
{
    int e = blockIdx.x * blockDim.x + threadIdx.x;
    if (e < N_EDGES) {
        int s = src[e], d = dst[e];
        float nm = dis[s] * w[e] * dis[d];
        int pos = atomicAdd(cursor + d, 1);
        int2 pk;
        pk.x = s;
        pk.y = __builtin_bit_cast(int, nm);
        csr[pos] = pk;
    }
}

// ---------------------------------------------------------------------------
// Aggregate BN0(h) over the graph at width 5 (fused BN0 apply).
// ---------------------------------------------------------------------------
__global__ __launch_bounds__(256) void k_agg0(const float* __restrict__ h,
                                              const float* __restrict__ stats,
                                              const float* __restrict__ g0,
                                              const float* __restrict__ be0,
                                              const int* __restrict__ rowptr,
                                              const int2* __restrict__ csr,
                                              const float* __restrict__ dis,
                                              float* __restrict__ agg)
{
    int n = blockIdx.x * blockDim.x + threadIdx.x;
    if (n >= N_NODES) return;
    float sc[D_IN], sh[D_IN];
#pragma unroll
    for (int f = 0; f < D_IN; ++f) {
        float m = stats[f] * (1.0f / N_NODES);
        float var = stats[D_IN + f] * (1.0f / N_NODES) - m * m;
        sc[f] = rsqrtf(var + BN_EPS) * g0[f];
        sh[f] = be0[f] - m * sc[f];
    }
    float dn = dis[n];
    float sl = dn * dn;
    float acc[D_IN];
#pragma unroll
    for (int f = 0; f < D_IN; ++f)
        acc[f] = sl * (h[n * D_IN + f] * sc[f] + sh[f]);
    int e0 = rowptr[n], e1 = rowptr[n + 1];
    for (int e = e0; e < e1; ++e) {
        int2 pk = csr[e];
        int s = pk.x;
        float nm = __builtin_bit_cast(float, pk.y);
#pragma unroll
        for (int f = 0; f < D_IN; ++f)
            acc[f] += nm * (h[s * D_IN + f] * sc[f] + sh[f]);
    }
#pragma unroll
    for (int f = 0; f < D_IN; ++f)
        agg[n * D_IN + f] = acc[f];
}

// ---------------------------------------------------------------------------
// Layer-1 skinny GEMM: x1 = agg0 @ W1 + b1  (K=5), fused BN1 stats.
// MUST be launched with exactly 512 blocks x 256 threads.
// ---------------------------------------------------------------------------
__global__ __launch_bounds__(256) void k_l1(const float* __restrict__ agg,
                                            const float* __restrict__ W1,
                                            const float* __restrict__ b1,
                                            float* __restrict__ x,
                                            float* __restrict__ stats)
{
    __shared__ float sm_s[256], sm_q[256];
    int t = threadIdx.x;
    int idx0 = blockIdx.x * 256 + t;
    int f = idx0 & (D_H - 1);
    float w[D_IN];
#pragma unroll
    for (int k = 0; k < D_IN; ++k) w[k] = W1[k * D_H + f];
    float b = b1[f];
    float s = 0.f, q = 0.f;
    const int stride = 512 * 256;
    for (int idx = idx0; idx < N_NODES * D_H; idx += stride) {
        int n = idx >> 7;
        const float* a = agg + n * D_IN;
        float v = b;
#pragma unroll
        for (int k = 0; k < D_IN; ++k) v += w[k] * a[k];
        x[idx] = v;
        s += v;
        q += v * v;
    }
    sm_s[t] = s;
    sm_q[t] = q;
    __syncthreads();
    if (t < D_H) {
        atomicAdd(stats + t, sm_s[t] + sm_s[t + D_H]);
        atomicAdd(stats + D_H + t, sm_q[t] + sm_q[t + D_H]);
    }
}

// ---------------------------------------------------------------------------
// BN apply + ReLU, fp32 in -> bf16 out
// ---------------------------------------------------------------------------
__global__ __launch_bounds__(256) void k_bn_relu_f32_bf16(const float* __restrict__ x,
                                                          const float* __restrict__ stats,
                                                          const float* __restrict__ g,
                                                          const float* __restrict__ be,
                                                          unsigned short* __restrict__ y)
{
    int i4 = blockIdx.x * blockDim.x + threadIdx.x;
    if (i4 >= N_NODES * D_H / 4) return;
    int f0 = (i4 & 31) * 4;
    float4 s4 = *(const float4*)(stats + f0);
    float4 q4 = *(const float4*)(stats + D_H + f0);
    float4 g4 = *(const float4*)(g + f0);
    float4 b4 = *(const float4*)(be + f0);
    float4 v = *(const float4*)(x + (size_t)i4 * 4);
    const float inv = 1.0f / N_NODES;
    float m, var, sc, sh;
    float r0, r1, r2, r3;
    m = s4.x * inv; var = q4.x * inv - m * m; sc = rsqrtf(var + BN_EPS) * g4.x; sh = b4.x - m * sc;
    r0 = fmaxf(v.x * sc + sh, 0.f);
    m = s4.y * inv; var = q4.y * inv - m * m; sc = rsqrtf(var + BN_EPS) * g4.y; sh = b4.y - m * sc;
    r1 = fmaxf(v.y * sc + sh, 0.f);
    m = s4.z * inv; var = q4.z * inv - m * m; sc = rsqrtf(var + BN_EPS) * g4.z; sh = b4.z - m * sc;
    r2 = fmaxf(v.z * sc + sh, 0.f);
    m = s4.w * inv; var = q4.w * inv - m * m; sc = rsqrtf(var + BN_EPS) * g4.w; sh = b4.w - m * sc;
    r3 = fmaxf(v.w * sc + sh, 0.f);
    uint2 o;
    o.x = (unsigned)f2bfb(r0) | ((unsigned)f2bfb(r1) << 16);
    o.y = (unsigned)f2bfb(r2) | ((unsigned)f2bfb(r3) << 16);
    *(uint2*)(y + (size_t)i4 * 4) = o;
}

// ---------------------------------------------------------------------------
// BN apply + ReLU, bf16 in -> bf16 out
// ---------------------------------------------------------------------------
__global__ __launch_bounds__(256) void k_bn_relu_bf16_bf16(const unsigned short* __restrict__ x,
                                                           const float* __restrict__ stats,
                                                           const float* __restrict__ g,
                                                           const float* __restrict__ be,
                                                           unsigned short* __restrict__ y)
{
    int i4 = blockIdx.x * blockDim.x + threadIdx.x;
    if (i4 >= N_NODES * D_H / 4) return;
    int f0 = (i4 & 31) * 4;
    float4 s4 = *(const float4*)(stats + f0);
    float4 q4 = *(const float4*)(stats + D_H + f0);
    float4 g4 = *(const float4*)(g + f0);
    float4 b4 = *(const float4*)(be + f0);
    uint2 iv = *(const uint2*)(x + (size_t)i4 * 4);
    const float inv = 1.0f / N_NODES;
    float m, var, sc, sh;
    float r0, r1, r2, r3;
    m = s4.x * inv; var = q4.x * inv - m * m; sc = rsqrtf(var + BN_EPS) * g4.x; sh = b4.x - m * sc;
    r0 = fmaxf(bflo(iv.x) * sc + sh, 0.f);
    m = s4.y * inv; var = q4.y * inv - m * m; sc = rsqrtf(var + BN_EPS) * g4.y; sh = b4.y - m * sc;
    r1 = fmaxf(bfhi(iv.x) * sc + sh, 0.f);
    m = s4.z * inv; var = q4.z * inv - m * m; sc = rsqrtf(var + BN_EPS) * g4.z; sh = b4.z - m * sc;
    r2 = fmaxf(bflo(iv.y) * sc + sh, 0.f);
    m = s4.w * inv; var = q4.w * inv - m * m; sc = rsqrtf(var + BN_EPS) * g4.w; sh = b4.w - m * sc;
    r3 = fmaxf(bfhi(iv.y) * sc + sh, 0.f);
    uint2 o;
    o.x = (unsigned)f2bfb(r0) | ((unsigned)f2bfb(r1) << 16);
    o.y = (unsigned)f2bfb(r2) | ((unsigned)f2bfb(r3) << 16);
    *(uint2*)(y + (size_t)i4 * 4) = o;
}

// ---------------------------------------------------------------------------
// 128-wide graph aggregation via CSR, bf16 in -> bf16 out, fp32 accumulate.
// ---------------------------------------------------------------------------
__global__ __launch_bounds__(256) void k_agg128(const unsigned short* __restrict__ h,
                                                const int* __restrict__ rowptr,
                                                const int2* __restrict__ csr,
                                                const float* __restrict__ dis,
                                                unsigned short* __restrict__ outb)
{
    int t = threadIdx.x;
    int n = blockIdx.x * 16 + (t >> 4);
    int f0 = (t & 15) * 8;
    if (n >= N_NODES) return;
    float d = dis[n];
    float sl = d * d;
    uint4 hv = *(const uint4*)(h + (size_t)n * D_H + f0);
    float a0 = sl * bflo(hv.x), a1 = sl * bfhi(hv.x);
    float a2 = sl * bflo(hv.y), a3 = sl * bfhi(hv.y);
    float a4 = sl * bflo(hv.z), a5 = sl * bfhi(hv.z);
    float a6 = sl * bflo(hv.w), a7 = sl * bfhi(hv.w);
    int e = rowptr[n], e1 = rowptr[n + 1];
    for (; e + 4 <= e1; e += 4) {
        int2 p0 = csr[e + 0], p1 = csr[e + 1], p2 = csr[e + 2], p3 = csr[e + 3];
        float w0 = __builtin_bit_cast(float, p0.y);
        float w1 = __builtin_bit_cast(float, p1.y);
        float w2 = __builtin_bit_cast(float, p2.y);
        float w3 = __builtin_bit_cast(float, p3.y);
        uint4 v0 = *(const uint4*)(h + (size_t)p0.x * D_H + f0);
        uint4 v1 = *(const uint4*)(h + (size_t)p1.x * D_H + f0);
        uint4 v2 = *(const uint4*)(h + (size_t)p2.x * D_H + f0);
        uint4 v3 = *(const uint4*)(h + (size_t)p3.x * D_H + f0);
        a0 += w0 * bflo(v0.x) + w1 * bflo(v1.x) + w2 * bflo(v2.x) + w3 * bflo(v3.x);
        a1 += w0 * bfhi(v0.x) + w1 * bfhi(v1.x) + w2 * bfhi(v2.x) + w3 * bfhi(v3.x);
        a2 += w0 * bflo(v0.y) + w1 * bflo(v1.y) + w2 * bflo(v2.y) + w3 * bflo(v3.y);
        a3 += w0 * bfhi(v0.y) + w1 * bfhi(v1.y) + w2 * bfhi(v2.y) + w3 * bfhi(v3.y);
        a4 += w0 * bflo(v0.z) + w1 * bflo(v1.z) + w2 * bflo(v2.z) + w3 * bflo(v3.z);
        a5 += w0 * bfhi(v0.z) + w1 * bfhi(v1.z) + w2 * bfhi(v2.z) + w3 * bfhi(v3.z);
        a6 += w0 * bflo(v0.w) + w1 * bflo(v1.w) + w2 * bflo(v2.w) + w3 * bflo(v3.w);
        a7 += w0 * bfhi(v0.w) + w1 * bfhi(v1.w) + w2 * bfhi(v2.w) + w3 * bfhi(v3.w);
    }
    for (; e < e1; ++e) {
        int2 pk = csr[e];
        float nm = __builtin_bit_cast(float, pk.y);
        uint4 v = *(const uint4*)(h + (size_t)pk.x * D_H + f0);
        a0 += nm * bflo(v.x); a1 += nm * bfhi(v.x);
        a2 += nm * bflo(v.y); a3 += nm * bfhi(v.y);
        a4 += nm * bflo(v.z); a5 += nm * bfhi(v.z);
        a6 += nm * bflo(v.w); a7 += nm * bfhi(v.w);
    }
    uint4 o;
    o.x = (unsigned)f2bfb(a0) | ((unsigned)f2bfb(a1) << 16);
    o.y = (unsigned)f2bfb(a2) | ((unsigned)f2bfb(a3) << 16);
    o.z = (unsigned)f2bfb(a4) | ((unsigned)f2bfb(a5) << 16);
    o.w = (unsigned)f2bfb(a6) | ((unsigned)f2bfb(a7) << 16);
    *(uint4*)(outb + (size_t)n * D_H + f0) = o;
}

// ---------------------------------------------------------------------------
// MFMA GEMM, LDS-staged B: C_bf16[N,128] = A_bf16[N,128] @ W + bias,
// fused BN stats. 64 rows/block, 4 waves.
// ---------------------------------------------------------------------------
__global__ __launch_bounds__(256) void k_gemm_mf(const unsigned short* __restrict__ A,
                                                 const unsigned short* __restrict__ Bt,
                                                 const float* __restrict__ bias,
                                                 unsigned short* __restrict__ C,
                                                 float* __restrict__ stats)
{
    __shared__ uint4 ldsB[2048];          // 32 KB fragment-major B
    __shared__ float sm_s[D_H], sm_q[D_H];
    int t = threadIdx.x;
    if (t < D_H) { sm_s[t] = 0.f; sm_q[t] = 0.f; }
    stage_b(Bt, ldsB, t);
    int wave = t >> 6, lane = t & 63;
    int m = lane & 15, quad = lane >> 4;
    int r0 = blockIdx.x * 64 + wave * 16;
    int arow = r0 + m < N_NODES ? r0 + m : N_NODES - 1;
    const bf16x8* ap = (const bf16x8*)(A + (size_t)arow * D_H + quad * 8);
    bf16x8 af[4];
#pragma unroll
    for (int ks = 0; ks < 4; ++ks) af[ks] = ap[ks * 4];
    __syncthreads();
    const bf16x8* bf = (const bf16x8*)ldsB;       // [fid*64 + lane]
    f32x4 acc[8];
#pragma unroll
    for (int ct = 0; ct < 8; ++ct) acc[ct] = (f32x4)(0.f);
#pragma unroll
    for (int ks = 0; ks < 4; ++ks) {
#pragma unroll
        for (int ct = 0; ct < 8; ++ct) {
            acc[ct] = __builtin_amdgcn_mfma_f32_16x16x32_bf16(
                af[ks], bf[(ct * 4 + ks) * 64 + lane], acc[ct], 0, 0, 0);
        }
    }
#pragma unroll
    for (int ct = 0; ct < 8; ++ct) {
        int col = ct * 16 + m;
        float bv = bias[col];
        float s = 0.f, q = 0.f;
#pragma unroll
        for (int r = 0; r < 4; ++r) {
            int rr = r0 + quad * 4 + r;
            if (rr < N_NODES) {
                float v = acc[ct][r] + bv;
                C[(size_t)rr * D_H + col] = f2bfb(v);
                s += v; q += v * v;
            }
        }
        atomicAdd(&sm_s[col], s);
        atomicAdd(&sm_q[col], q);
    }
    __syncthreads();
    if (t < D_H) {
        atomicAdd(stats + t, sm_s[t]);
        atomicAdd(stats + D_H + t, sm_q[t]);
    }
}

// ---------------------------------------------------------------------------
// MFMA dual GEMM, LDS-staged B (one matrix at a time):
// mu = A@Wmu+bmu -> out, ls = A@Wls+bls -> out + N*128. fp32 out.
// ---------------------------------------------------------------------------
__global__ __launch_bounds__(256) void k_gemm_out_mf(const unsigned short* __restrict__ A,
                                                     const unsigned short* __restrict__ Btmu,
                                                     const float* __restrict__ bmu,
                                                     const unsigned short* __restrict__ Btls,
                                                     const float* __restrict__ bls,
                                                     float* __restrict__ out)
{
    __shared__ uint4 ldsB[2048];          // 32 KB fragment-major B
    int t = threadIdx.x;
    int wave = t >> 6, lane = t & 63;
    int m = lane & 15, quad = lane >> 4;
    int r0 = blockIdx.x * 64 + wave * 16;
    int arow = r0 + m < N_NODES ? r0 + m : N_NODES - 1;
    const bf16x8* ap = (const bf16x8*)(A + (size_t)arow * D_H + quad * 8);
    bf16x8 af[4];
#pragma unroll
    for (int ks = 0; ks < 4; ++ks) af[ks] = ap[ks * 4];
    const bf16x8* bf = (const bf16x8*)ldsB;
#pragma unroll
    for (int half = 0; half < 2; ++half) {
        if (half) __syncthreads();        // protect restage vs prior reads
        stage_b(half ? Btls : Btmu, ldsB, t);
        __syncthreads();
        const float* bias = half ? bls : bmu;
        float* C = out + (half ? (size_t)N_NODES * D_H : 0);
        f32x4 acc[8];
#pragma unroll
        for (int ct = 0; ct < 8; ++ct) acc[ct] = (f32x4)(0.f);
#pragma unroll
        for (int ks = 0; ks < 4; ++ks) {
#pragma unroll
            for (int ct = 0; ct < 8; ++ct) {
                acc[ct] = __builtin_amdgcn_mfma_f32_16x16x32_bf16(
                    af[ks], bf[(ct * 4 + ks) * 64 + lane], acc[ct], 0, 0, 0);
            }
        }
#pragma unroll
        for (int ct = 0; ct < 8; ++ct) {
            int col = ct * 16 + m;
            float bv = bias[col];
#pragma unroll
            for (int r = 0; r < 4; ++r) {
                int rr = r0 + quad * 4 + r;
                if (rr < N_NODES)
                    C[(size_t)rr * D_H + col] = acc[ct][r] + bv;
            }
        }
    }
}

// ---------------------------------------------------------------------------
extern "C" void kernel_launch(void* const* d_in, const int* in_sizes, int n_in,
                              void* d_out, int out_size, void* d_ws, size_t ws_size,
                              hipStream_t stream)
{
    const float* h   = (const float*)d_in[0];
    const int*   eidx = (const int*)d_in[1];
    const float* ew  = (const float*)d_in[2];
    const float* g0  = (const float*)d_in[3];
    const float* be0 = (const float*)d_in[4];
    const float* W1  = (const float*)d_in[5];
    const float* b1  = (const float*)d_in[6];
    const float* g1  = (const float*)d_in[7];
    const float* be1 = (const float*)d_in[8];
    const float* W2  = (const float*)d_in[9];
    const float* b2  = (const float*)d_in[10];
    const float* g2  = (const float*)d_in[11];
    const float* be2 = (const float*)d_in[12];
    const float* Wmu = (const float*)d_in[13];
    const float* bmu = (const float*)d_in[14];
    const float* Wls = (const float*)d_in[15];
    const float* bls = (const float*)d_in[16];
    const int* srcv = eidx;
    const int* dstv = eidx + N_EDGES;
    float* out = (float*)d_out;

    char* ws = (char*)d_ws;
    size_t off = 0;
    auto alloc = [&](size_t bytes) -> char* {
        char* p = ws + off;
        off += (bytes + 255) & ~(size_t)255;
        return p;
    };
    float* stats0  = (float*)alloc(16 * 4);
    float* stats1  = (float*)alloc(256 * 4);
    float* stats2  = (float*)alloc(256 * 4);
    unsigned long long* degcnt = (unsigned long long*)alloc(N_NODES * 8);
    size_t zero_bytes = off;                 // everything above must start at 0
    int*   rowptr  = (int*)  alloc((N_NODES + 1) * 4);
    float* dis     = (float*)alloc(N_NODES * 4);
    int*   cursor  = (int*)  alloc(N_NODES * 4);
    int*   blocksums = (int*)alloc(256 * 4);
    int2*  csr     = (int2*) alloc((size_t)N_EDGES * 8);
    float* agg0    = (float*)alloc(N_NODES * D_IN * 4);
    float* bufA    = (float*)alloc((size_t)N_NODES * D_H * 4);                  // fp32 pre-BN1
    unsigned short* bufAh = (unsigned short*)alloc((size_t)N_NODES * D_H * 2);  // bf16
    unsigned short* bufBh = (unsigned short*)alloc((size_t)N_NODES * D_H * 2);  // bf16
    unsigned short* Wt2   = (unsigned short*)alloc(D_H * D_H * 2);
    unsigned short* Wtmu  = (unsigned short*)alloc(D_H * D_H * 2);
    unsigned short* Wtls  = (unsigned short*)alloc(D_H * D_H * 2);
    (void)ws_size; (void)in_sizes; (void)n_in; (void)out_size;

    hipMemsetAsync(d_ws, 0, zero_bytes, stream);

    k_wprep<<<192, 256, 0, stream>>>(W2, Wmu, Wls, Wt2, Wtmu, Wtls);
    k_bn0_stats<<<(N_NODES + 255) / 256, 256, 0, stream>>>(h, stats0);
    k_deg_count<<<(N_EDGES + 255) / 256, 256, 0, stream>>>(dstv, ew, degcnt);
    k_scan1<<<SCAN_BLOCKS, 256, 0, stream>>>(degcnt, dis, blocksums);
    k_scan2<<<1, 256, 0, stream>>>(blocksums, rowptr);
    k_scan3<<<SCAN_BLOCKS, 256, 0, stream>>>(degcnt, rowptr, cursor, blocksums);
    k_fill<<<(N_EDGES + 255) / 256, 256, 0, stream>>>(srcv, dstv, ew, dis, cursor, csr);
    k_agg0<<<(N_NODES + 255) / 256, 256, 0, stream>>>(h, stats0, g0, be0, rowptr,
                                                      csr, dis, agg0);
    k_l1<<<512, 256, 0, stream>>>(agg0, W1, b1, bufA, stats1);
    k_bn_relu_f32_bf16<<<(N_NODES * D_H / 4 + 255) / 256, 256, 0, stream>>>(bufA, stats1, g1, be1, bufAh);
    k_agg128<<<(N_NODES + 15) / 16, 256, 0, stream>>>(bufAh, rowptr, csr, dis, bufBh);
    k_gemm_mf<<<(N_NODES + 63) / 64, 256, 0, stream>>>(bufBh, Wt2, b2, bufAh, stats2);
    k_bn_relu_bf16_bf16<<<(N_NODES * D_H / 4 + 255) / 256, 256, 0, stream>>>(bufAh, stats2, g2, be2, bufBh);
    k_gemm_out_mf<<<(N_NODES + 63) / 64, 256, 0, stream>>>(bufBh, Wtmu, bmu, Wtls, bls, out);
}

// Round 7
// 281.476 us; speedup vs baseline: 2.3704x; 1.1570x over previous
//
#include <hip/hip_runtime.h>

#define N_NODES 50000
#define N_EDGES 600000
#define D_IN 5
#define D_H 128
#define BN_EPS 1e-5f
#define SCAN_BLOCKS ((N_NODES + 255) / 256)   // 196
#define DEG_BLOCKS ((N_EDGES + 255) / 256)    // 2344
#define FIX_SCALE 16777216.0f                  // 2^24
#define FIX_INV   (1.0f / 16777216.0f)

typedef __bf16 bf16x8 __attribute__((ext_vector_type(8)));
typedef float  f32x4  __attribute__((ext_vector_type(4)));

__device__ inline unsigned short f2bfb(float f) {          // fp32 -> bf16 bits, RNE
    unsigned u = __builtin_bit_cast(unsigned, f);
    unsigned r = u + 0x7fffu + ((u >> 16) & 1u);
    return (unsigned short)(r >> 16);
}
__device__ inline float bflo(unsigned u) { return __builtin_bit_cast(float, u << 16); }
__device__ inline float bfhi(unsigned u) { return __builtin_bit_cast(float, u & 0xffff0000u); }

// ---------------------------------------------------------------------------
// Stage Bt[128][128] bf16 into LDS fragment-major: frag fid=ct*4+ks at
// fid*1024 bytes; lane l's 16 B at fid*1024+l*16.
// ---------------------------------------------------------------------------
__device__ inline void stage_b(const unsigned short* __restrict__ Bt,
                               uint4* __restrict__ lds, int t)
{
#pragma unroll
    for (int i = 0; i < 8; ++i) {
        int slot = i * 256 + t;          // 0..2047
        int fid = slot >> 6;
        int l = slot & 63;
        int row = (fid >> 2) * 16 + (l & 15);
        int boff = ((l >> 4) * 16 + (fid & 3) * 64) >> 1;   // in shorts
        lds[slot] = *(const uint4*)(Bt + row * D_H + boff);
    }
}

// ---------------------------------------------------------------------------
// Fused prep: [0,192) weight transpose+bf16; [192,388) BN0 stats;
// [388, 388+DEG_BLOCKS) per-edge u64 deg/count atomic + rank capture.
// ---------------------------------------------------------------------------
__global__ __launch_bounds__(256) void k_prep(const float* __restrict__ W2,
                                              const float* __restrict__ Wmu,
                                              const float* __restrict__ Wls,
                                              unsigned short* __restrict__ T2,
                                              unsigned short* __restrict__ Tmu,
                                              unsigned short* __restrict__ Tls,
                                              const float* __restrict__ h,
                                              float* __restrict__ stats0,
                                              const int* __restrict__ dst,
                                              const float* __restrict__ w,
                                              unsigned long long* __restrict__ degcnt,
                                              int* __restrict__ rank)
{
    __shared__ float ss[D_IN], sq[D_IN];
    int b = blockIdx.x;
    int t = threadIdx.x;
    if (b < 192) {
        int mat = b >> 6;
        int idx = (b & 63) * 256 + t;   // < 16384
        const float* W = (mat == 0) ? W2 : (mat == 1) ? Wmu : Wls;
        unsigned short* T = (mat == 0) ? T2 : (mat == 1) ? Tmu : Tls;
        int k = idx >> 7, n = idx & 127;
        T[n * D_H + k] = f2bfb(W[idx]);
    } else if (b < 192 + SCAN_BLOCKS) {
        if (t < D_IN) { ss[t] = 0.f; sq[t] = 0.f; }
        __syncthreads();
        int node = (b - 192) * 256 + t;
        float v[D_IN];
#pragma unroll
        for (int f = 0; f < D_IN; ++f)
            v[f] = (node < N_NODES) ? h[node * D_IN + f] : 0.f;
        int lane = t & 63;
#pragma unroll
        for (int f = 0; f < D_IN; ++f) {
            float s = v[f], q = v[f] * v[f];
            for (int off = 32; off > 0; off >>= 1) {
                s += __shfl_down(s, off);
                q += __shfl_down(q, off);
            }
            if (lane == 0) { atomicAdd(&ss[f], s); atomicAdd(&sq[f], q); }
        }
        __syncthreads();
        if (t < D_IN) {
            atomicAdd(&stats0[t], ss[t]);
            atomicAdd(&stats0[D_IN + t], sq[t]);
        }
    } else {
        int e = (b - 192 - SCAN_BLOCKS) * 256 + t;
        if (e < N_EDGES) {
            int d = dst[e];
            unsigned long long fx = (unsigned long long)(w[e] * FIX_SCALE + 0.5f);
            unsigned long long old = atomicAdd(degcnt + d, (1ull << 40) | fx);
            rank[e] = (int)(old >> 40);
        }
    }
}

// ---------------------------------------------------------------------------
__global__ __launch_bounds__(256) void k_scan1(const unsigned long long* __restrict__ degcnt,
                                               float* __restrict__ dis,
                                               int* __restrict__ blocksums)
{
    __shared__ int sm[256];
    int t = threadIdx.x;
    int i = blockIdx.x * 256 + t;
    int c = 0;
    if (i < N_NODES) {
        unsigned long long v = degcnt[i];
        c = (int)(v >> 40);
        float deg = (float)(v & ((1ull << 40) - 1)) * FIX_INV;
        dis[i] = rsqrtf(deg + 1.0f);
    }
    sm[t] = c;
    __syncthreads();
    for (int off = 128; off > 0; off >>= 1) {
        if (t < off) sm[t] += sm[t + off];
        __syncthreads();
    }
    if (t == 0) blocksums[blockIdx.x] = sm[0];
}

__global__ __launch_bounds__(256) void k_scan2(int* __restrict__ blocksums,
                                               int* __restrict__ rowptr)
{
    __shared__ int sm[256];
    int t = threadIdx.x;
    int c = (t < SCAN_BLOCKS) ? blocksums[t] : 0;
    sm[t] = c;
    __syncthreads();
    for (int off = 1; off < 256; off <<= 1) {
        int v = (t >= off) ? sm[t - off] : 0;
        __syncthreads();
        sm[t] += v;
        __syncthreads();
    }
    if (t < SCAN_BLOCKS) blocksums[t] = sm[t] - c;
    if (t == 255) rowptr[N_NODES] = sm[255];
}

__global__ __launch_bounds__(256) void k_scan3(const unsigned long long* __restrict__ degcnt,
                                               int* __restrict__ rowptr,
                                               const int* __restrict__ blocksums)
{
    __shared__ int sm[256];
    int t = threadIdx.x;
    int i = blockIdx.x * 256 + t;
    int c = (i < N_NODES) ? (int)(degcnt[i] >> 40) : 0;
    sm[t] = c;
    __syncthreads();
    for (int off = 1; off < 256; off <<= 1) {
        int v = (t >= off) ? sm[t - off] : 0;
        __syncthreads();
        sm[t] += v;
        __syncthreads();
    }
    if (i < N_NODES)
        rowptr[i] = blocksums[blockIdx.x] + sm[t] - c;
}

// ---------------------------------------------------------------------------
// Fill CSR, atomic-free: pos = rowptr[dst] + rank. csr = {src, dis[src]*w}
// (dis[dst] factored out into the aggregation epilogue).
// ---------------------------------------------------------------------------
__global__ __launch_bounds__(256) void k_fill(const int* __restrict__ src,
                                              const int* __restrict__ dst,
                                              const float* __restrict__ w,
                                              const float* __restrict__ dis,
                                              const int* __restrict__ rowptr,
                                              const int* __restrict__ rank,
                                              int2* __restrict__ csr)
{
    int e = blockIdx.x * blockDim.x + threadIdx.x;
    if (e < N_EDGES) {
        int s = src[e], d = dst[e];
        float pn = dis[s] * w[e];
        int pos = rowptr[d] + rank[e];
        int2 pk;
        pk.x = s;
        pk.y = __builtin_bit_cast(int, pn);
        csr[pos] = pk;
    }
}

// ---------------------------------------------------------------------------
// Aggregate BN0(h) at width 5. out[n] = dis[n]*(dis[n]*bn(h[n]) + sum pn*bn(h[s]))
// ---------------------------------------------------------------------------
__global__ __launch_bounds__(256) void k_agg0(const float* __restrict__ h,
                                              const float* __restrict__ stats,
                                              const float* __restrict__ g0,
                                              const float* __restrict__ be0,
                                              const int* __restrict__ rowptr,
                                              const int2* __restrict__ csr,
                                              const float* __restrict__ dis,
                                              float* __restrict__ agg)
{
    int n = blockIdx.x * blockDim.x + threadIdx.x;
    if (n >= N_NODES) return;
    float sc[D_IN], sh[D_IN];
#pragma unroll
    for (int f = 0; f < D_IN; ++f) {
        float m = stats[f] * (1.0f / N_NODES);
        float var = stats[D_IN + f] * (1.0f / N_NODES) - m * m;
        sc[f] = rsqrtf(var + BN_EPS) * g0[f];
        sh[f] = be0[f] - m * sc[f];
    }
    float dn = dis[n];
    float acc[D_IN];
#pragma unroll
    for (int f = 0; f < D_IN; ++f)
        acc[f] = dn * (h[n * D_IN + f] * sc[f] + sh[f]);
    int e0 = rowptr[n], e1 = rowptr[n + 1];
    for (int e = e0; e < e1; ++e) {
        int2 pk = csr[e];
        int s = pk.x;
        float pn = __builtin_bit_cast(float, pk.y);
#pragma unroll
        for (int f = 0; f < D_IN; ++f)
            acc[f] += pn * (h[s * D_IN + f] * sc[f] + sh[f]);
    }
#pragma unroll
    for (int f = 0; f < D_IN; ++f)
        agg[n * D_IN + f] = dn * acc[f];
}

// ---------------------------------------------------------------------------
// Layer-1 skinny GEMM (K=5), bf16 output (pre-BN), fused BN1 stats (fp32).
// MUST be launched with exactly 512 blocks x 256 threads.
// ---------------------------------------------------------------------------
__global__ __launch_bounds__(256) void k_l1(const float* __restrict__ agg,
                                            const float* __restrict__ W1,
                                            const float* __restrict__ b1,
                                            unsigned short* __restrict__ x,
                                            float* __restrict__ stats)
{
    __shared__ float sm_s[D_H], sm_q[D_H];
    int t = threadIdx.x;
    if (t < D_H) { sm_s[t] = 0.f; sm_q[t] = 0.f; }
    __syncthreads();
    int idx0 = blockIdx.x * 256 + t;
    int f0 = (idx0 & 63) * 2;      // feature pair, constant per thread
    float wa[D_IN], wb[D_IN];
#pragma unroll
    for (int k = 0; k < D_IN; ++k) {
        wa[k] = W1[k * D_H + f0];
        wb[k] = W1[k * D_H + f0 + 1];
    }
    float ba = b1[f0], bb = b1[f0 + 1];
    float s0 = 0.f, q0 = 0.f, s1 = 0.f, q1 = 0.f;
    const int stride = 512 * 256;
    for (int idx = idx0; idx < N_NODES * 64; idx += stride) {
        int n = idx >> 6;
        const float* a = agg + n * D_IN;
        float v0 = ba, v1 = bb;
#pragma unroll
        for (int k = 0; k < D_IN; ++k) { v0 += wa[k] * a[k]; v1 += wb[k] * a[k]; }
        ((unsigned*)x)[idx] = (unsigned)f2bfb(v0) | ((unsigned)f2bfb(v1) << 16);
        s0 += v0; q0 += v0 * v0; s1 += v1; q1 += v1 * v1;
    }
    atomicAdd(&sm_s[f0], s0); atomicAdd(&sm_s[f0 + 1], s1);
    atomicAdd(&sm_q[f0], q0); atomicAdd(&sm_q[f0 + 1], q1);
    __syncthreads();
    if (t < D_H) {
        atomicAdd(stats + t, sm_s[t]);
        atomicAdd(stats + D_H + t, sm_q[t]);
    }
}

// ---------------------------------------------------------------------------
// 128-wide aggregation, fused BN1+ReLU on gathered elements.
// out[n] = dis[n]*(dis[n]*bnrelu(x[n]) + sum pn*bnrelu(x[s])), bf16 out.
// ---------------------------------------------------------------------------
__global__ __launch_bounds__(256) void k_agg128(const unsigned short* __restrict__ x,
                                                const float* __restrict__ stats,
                                                const float* __restrict__ g,
                                                const float* __restrict__ be,
                                                const int* __restrict__ rowptr,
                                                const int2* __restrict__ csr,
                                                const float* __restrict__ dis,
                                                unsigned short* __restrict__ outb)
{
    int t = threadIdx.x;
    int n = blockIdx.x * 16 + (t >> 4);
    int f0 = (t & 15) * 8;
    if (n >= N_NODES) return;
    float sc[8], sh[8];
    const float inv = 1.0f / N_NODES;
#pragma unroll
    for (int j = 0; j < 8; ++j) {
        float m = stats[f0 + j] * inv;
        float var = stats[D_H + f0 + j] * inv - m * m;
        sc[j] = rsqrtf(var + BN_EPS) * g[f0 + j];
        sh[j] = be[f0 + j] - m * sc[j];
    }
#define BNR(val, j) fmaxf((val) * sc[j] + sh[j], 0.f)
    float dn = dis[n];
    uint4 hv = *(const uint4*)(x + (size_t)n * D_H + f0);
    float a0 = dn * BNR(bflo(hv.x), 0), a1 = dn * BNR(bfhi(hv.x), 1);
    float a2 = dn * BNR(bflo(hv.y), 2), a3 = dn * BNR(bfhi(hv.y), 3);
    float a4 = dn * BNR(bflo(hv.z), 4), a5 = dn * BNR(bfhi(hv.z), 5);
    float a6 = dn * BNR(bflo(hv.w), 6), a7 = dn * BNR(bfhi(hv.w), 7);
    int e = rowptr[n], e1 = rowptr[n + 1];
    for (; e + 4 <= e1; e += 4) {
        int2 p0 = csr[e + 0], p1 = csr[e + 1], p2 = csr[e + 2], p3 = csr[e + 3];
        float w0 = __builtin_bit_cast(float, p0.y);
        float w1 = __builtin_bit_cast(float, p1.y);
        float w2 = __builtin_bit_cast(float, p2.y);
        float w3 = __builtin_bit_cast(float, p3.y);
        uint4 v0 = *(const uint4*)(x + (size_t)p0.x * D_H + f0);
        uint4 v1 = *(const uint4*)(x + (size_t)p1.x * D_H + f0);
        uint4 v2 = *(const uint4*)(x + (size_t)p2.x * D_H + f0);
        uint4 v3 = *(const uint4*)(x + (size_t)p3.x * D_H + f0);
        a0 += w0 * BNR(bflo(v0.x), 0) + w1 * BNR(bflo(v1.x), 0) + w2 * BNR(bflo(v2.x), 0) + w3 * BNR(bflo(v3.x), 0);
        a1 += w0 * BNR(bfhi(v0.x), 1) + w1 * BNR(bfhi(v1.x), 1) + w2 * BNR(bfhi(v2.x), 1) + w3 * BNR(bfhi(v3.x), 1);
        a2 += w0 * BNR(bflo(v0.y), 2) + w1 * BNR(bflo(v1.y), 2) + w2 * BNR(bflo(v2.y), 2) + w3 * BNR(bflo(v3.y), 2);
        a3 += w0 * BNR(bfhi(v0.y), 3) + w1 * BNR(bfhi(v1.y), 3) + w2 * BNR(bfhi(v2.y), 3) + w3 * BNR(bfhi(v3.y), 3);
        a4 += w0 * BNR(bflo(v0.z), 4) + w1 * BNR(bflo(v1.z), 4) + w2 * BNR(bflo(v2.z), 4) + w3 * BNR(bflo(v3.z), 4);
        a5 += w0 * BNR(bfhi(v0.z), 5) + w1 * BNR(bfhi(v1.z), 5) + w2 * BNR(bfhi(v2.z), 5) + w3 * BNR(bfhi(v3.z), 5);
        a6 += w0 * BNR(bflo(v0.w), 6) + w1 * BNR(bflo(v1.w), 6) + w2 * BNR(bflo(v2.w), 6) + w3 * BNR(bflo(v3.w), 6);
        a7 += w0 * BNR(bfhi(v0.w), 7) + w1 * BNR(bfhi(v1.w), 7) + w2 * BNR(bfhi(v2.w), 7) + w3 * BNR(bfhi(v3.w), 7);
    }
    for (; e < e1; ++e) {
        int2 pk = csr[e];
        float pn = __builtin_bit_cast(float, pk.y);
        uint4 v = *(const uint4*)(x + (size_t)pk.x * D_H + f0);
        a0 += pn * BNR(bflo(v.x), 0); a1 += pn * BNR(bfhi(v.x), 1);
        a2 += pn * BNR(bflo(v.y), 2); a3 += pn * BNR(bfhi(v.y), 3);
        a4 += pn * BNR(bflo(v.z), 4); a5 += pn * BNR(bfhi(v.z), 5);
        a6 += pn * BNR(bflo(v.w), 6); a7 += pn * BNR(bfhi(v.w), 7);
    }
#undef BNR
    uint4 o;
    o.x = (unsigned)f2bfb(dn * a0) | ((unsigned)f2bfb(dn * a1) << 16);
    o.y = (unsigned)f2bfb(dn * a2) | ((unsigned)f2bfb(dn * a3) << 16);
    o.z = (unsigned)f2bfb(dn * a4) | ((unsigned)f2bfb(dn * a5) << 16);
    o.w = (unsigned)f2bfb(dn * a6) | ((unsigned)f2bfb(dn * a7) << 16);
    *(uint4*)(outb + (size_t)n * D_H + f0) = o;
}

// ---------------------------------------------------------------------------
// MFMA GEMM, LDS-staged B: C_bf16 = A_bf16 @ W + bias (pre-BN), fused stats.
// ---------------------------------------------------------------------------
__global__ __launch_bounds__(256) void k_gemm_mf(const unsigned short* __restrict__ A,
                                                 const unsigned short* __restrict__ Bt,
                                                 const float* __restrict__ bias,
                                                 unsigned short* __restrict__ C,
                                                 float* __restrict__ stats)
{
    __shared__ uint4 ldsB[2048];          // 32 KB fragment-major B
    __shared__ float sm_s[D_H], sm_q[D_H];
    int t = threadIdx.x;
    if (t < D_H) { sm_s[t] = 0.f; sm_q[t] = 0.f; }
    stage_b(Bt, ldsB, t);
    int wave = t >> 6, lane = t & 63;
    int m = lane & 15, quad = lane >> 4;
    int r0 = blockIdx.x * 64 + wave * 16;
    int arow = r0 + m < N_NODES ? r0 + m : N_NODES - 1;
    const bf16x8* ap = (const bf16x8*)(A + (size_t)arow * D_H + quad * 8);
    bf16x8 af[4];
#pragma unroll
    for (int ks = 0; ks < 4; ++ks) af[ks] = ap[ks * 4];
    __syncthreads();
    const bf16x8* bf = (const bf16x8*)ldsB;       // [fid*64 + lane]
    f32x4 acc[8];
#pragma unroll
    for (int ct = 0; ct < 8; ++ct) acc[ct] = (f32x4)(0.f);
#pragma unroll
    for (int ks = 0; ks < 4; ++ks) {
#pragma unroll
        for (int ct = 0; ct < 8; ++ct) {
            acc[ct] = __builtin_amdgcn_mfma_f32_16x16x32_bf16(
                af[ks], bf[(ct * 4 + ks) * 64 + lane], acc[ct], 0, 0, 0);
        }
    }
#pragma unroll
    for (int ct = 0; ct < 8; ++ct) {
        int col = ct * 16 + m;
        float bv = bias[col];
        float s = 0.f, q = 0.f;
#pragma unroll
        for (int r = 0; r < 4; ++r) {
            int rr = r0 + quad * 4 + r;
            if (rr < N_NODES) {
                float v = acc[ct][r] + bv;
                C[(size_t)rr * D_H + col] = f2bfb(v);
                s += v; q += v * v;
            }
        }
        atomicAdd(&sm_s[col], s);
        atomicAdd(&sm_q[col], q);
    }
    __syncthreads();
    if (t < D_H) {
        atomicAdd(stats + t, sm_s[t]);
        atomicAdd(stats + D_H + t, sm_q[t]);
    }
}

// ---------------------------------------------------------------------------
// MFMA dual GEMM with fused BN2+ReLU on the A fragments.
// mu -> out[0:N*128), log_std -> out[N*128:). fp32 out.
// ---------------------------------------------------------------------------
__global__ __launch_bounds__(256) void k_gemm_out_mf(const unsigned short* __restrict__ A,
                                                     const float* __restrict__ stats,
                                                     const float* __restrict__ g,
                                                     const float* __restrict__ be,
                                                     const unsigned short* __restrict__ Btmu,
                                                     const float* __restrict__ bmu,
                                                     const unsigned short* __restrict__ Btls,
                                                     const float* __restrict__ bls,
                                                     float* __restrict__ out)
{
    __shared__ uint4 ldsB[2048];          // 32 KB fragment-major B
    int t = threadIdx.x;
    int wave = t >> 6, lane = t & 63;
    int m = lane & 15, quad = lane >> 4;
    int r0 = blockIdx.x * 64 + wave * 16;
    int arow = r0 + m < N_NODES ? r0 + m : N_NODES - 1;
    const unsigned short* arowp = A + (size_t)arow * D_H + quad * 8;
    const float inv = 1.0f / N_NODES;
    bf16x8 af[4];
#pragma unroll
    for (int ks = 0; ks < 4; ++ks) {
        uint4 av = *(const uint4*)(arowp + ks * 32);
        float vals[8] = { bflo(av.x), bfhi(av.x), bflo(av.y), bfhi(av.y),
                          bflo(av.z), bfhi(av.z), bflo(av.w), bfhi(av.w) };
        int fb = quad * 8 + ks * 32;
        unsigned short o[8];
#pragma unroll
        for (int j = 0; j < 8; ++j) {
            int f = fb + j;
            float mm = stats[f] * inv;
            float var = stats[D_H + f] * inv - mm * mm;
            float scv = rsqrtf(var + BN_EPS) * g[f];
            float shv = be[f] - mm * scv;
            o[j] = f2bfb(fmaxf(vals[j] * scv + shv, 0.f));
        }
        uint4 pk;
        pk.x = (unsigned)o[0] | ((unsigned)o[1] << 16);
        pk.y = (unsigned)o[2] | ((unsigned)o[3] << 16);
        pk.z = (unsigned)o[4] | ((unsigned)o[5] << 16);
        pk.w = (unsigned)o[6] | ((unsigned)o[7] << 16);
        af[ks] = __builtin_bit_cast(bf16x8, pk);
    }
    const bf16x8* bf = (const bf16x8*)ldsB;
#pragma unroll
    for (int half = 0; half < 2; ++half) {
        if (half) __syncthreads();        // protect restage vs prior reads
        stage_b(half ? Btls : Btmu, ldsB, t);
        __syncthreads();
        const float* bias = half ? bls : bmu;
        float* C = out + (half ? (size_t)N_NODES * D_H : 0);
        f32x4 acc[8];
#pragma unroll
        for (int ct = 0; ct < 8; ++ct) acc[ct] = (f32x4)(0.f);
#pragma unroll
        for (int ks = 0; ks < 4; ++ks) {
#pragma unroll
            for (int ct = 0; ct < 8; ++ct) {
                acc[ct] = __builtin_amdgcn_mfma_f32_16x16x32_bf16(
                    af[ks], bf[(ct * 4 + ks) * 64 + lane], acc[ct], 0, 0, 0);
            }
        }
#pragma unroll
        for (int ct = 0; ct < 8; ++ct) {
            int col = ct * 16 + m;
            float bv = bias[col];
#pragma unroll
            for (int r = 0; r < 4; ++r) {
                int rr = r0 + quad * 4 + r;
                if (rr < N_NODES)
                    C[(size_t)rr * D_H + col] = acc[ct][r] + bv;
            }
        }
    }
}

// ---------------------------------------------------------------------------
extern "C" void kernel_launch(void* const* d_in, const int* in_sizes, int n_in,
                              void* d_out, int out_size, void* d_ws, size_t ws_size,
                              hipStream_t stream)
{
    const float* h   = (const float*)d_in[0];
    const int*   eidx = (const int*)d_in[1];
    const float* ew  = (const float*)d_in[2];
    const float* g0  = (const float*)d_in[3];
    const float* be0 = (const float*)d_in[4];
    const float* W1  = (const float*)d_in[5];
    const float* b1  = (const float*)d_in[6];
    const float* g1  = (const float*)d_in[7];
    const float* be1 = (const float*)d_in[8];
    const float* W2  = (const float*)d_in[9];
    const float* b2  = (const float*)d_in[10];
    const float* g2  = (const float*)d_in[11];
    const float* be2 = (const float*)d_in[12];
    const float* Wmu = (const float*)d_in[13];
    const float* bmu = (const float*)d_in[14];
    const float* Wls = (const float*)d_in[15];
    const float* bls = (const float*)d_in[16];
    const int* srcv = eidx;
    const int* dstv = eidx + N_EDGES;
    float* out = (float*)d_out;

    char* ws = (char*)d_ws;
    size_t off = 0;
    auto alloc = [&](size_t bytes) -> char* {
        char* p = ws + off;
        off += (bytes + 255) & ~(size_t)255;
        return p;
    };
    float* stats0  = (float*)alloc(16 * 4);
    float* stats1  = (float*)alloc(256 * 4);
    float* stats2  = (float*)alloc(256 * 4);
    unsigned long long* degcnt = (unsigned long long*)alloc(N_NODES * 8);
    size_t zero_bytes = off;                 // everything above must start at 0
    int*   rowptr  = (int*)  alloc((N_NODES + 1) * 4);
    float* dis     = (float*)alloc(N_NODES * 4);
    int*   rank    = (int*)  alloc((size_t)N_EDGES * 4);
    int*   blocksums = (int*)alloc(256 * 4);
    int2*  csr     = (int2*) alloc((size_t)N_EDGES * 8);
    float* agg0    = (float*)alloc(N_NODES * D_IN * 4);
    unsigned short* x1h  = (unsigned short*)alloc((size_t)N_NODES * D_H * 2);  // bf16 pre-BN1
    unsigned short* aggh = (unsigned short*)alloc((size_t)N_NODES * D_H * 2);  // bf16 agg
    unsigned short* c2h  = (unsigned short*)alloc((size_t)N_NODES * D_H * 2);  // bf16 pre-BN2
    unsigned short* Wt2   = (unsigned short*)alloc(D_H * D_H * 2);
    unsigned short* Wtmu  = (unsigned short*)alloc(D_H * D_H * 2);
    unsigned short* Wtls  = (unsigned short*)alloc(D_H * D_H * 2);
    (void)ws_size; (void)in_sizes; (void)n_in; (void)out_size;

    hipMemsetAsync(d_ws, 0, zero_bytes, stream);

    k_prep<<<192 + SCAN_BLOCKS + DEG_BLOCKS, 256, 0, stream>>>(
        W2, Wmu, Wls, Wt2, Wtmu, Wtls, h, stats0, dstv, ew, degcnt, rank);
    k_scan1<<<SCAN_BLOCKS, 256, 0, stream>>>(degcnt, dis, blocksums);
    k_scan2<<<1, 256, 0, stream>>>(blocksums, rowptr);
    k_scan3<<<SCAN_BLOCKS, 256, 0, stream>>>(degcnt, rowptr, blocksums);
    k_fill<<<DEG_BLOCKS, 256, 0, stream>>>(srcv, dstv, ew, dis, rowptr, rank, csr);
    k_agg0<<<SCAN_BLOCKS, 256, 0, stream>>>(h, stats0, g0, be0, rowptr, csr, dis, agg0);
    k_l1<<<512, 256, 0, stream>>>(agg0, W1, b1, x1h, stats1);
    k_agg128<<<(N_NODES + 15) / 16, 256, 0, stream>>>(x1h, stats1, g1, be1,
                                                      rowptr, csr, dis, aggh);
    k_gemm_mf<<<(N_NODES + 63) / 64, 256, 0, stream>>>(aggh, Wt2, b2, c2h, stats2);
    k_gemm_out_mf<<<(N_NODES + 63) / 64, 256, 0, stream>>>(c2h, stats2, g2, be2,
                                                           Wtmu, bmu, Wtls, bls, out);
}